// Round 4
// baseline (2850.411 us; speedup 1.0000x reference)
//
#include <hip/hip_runtime.h>
#include <hip/hip_bf16.h>

#define D_MODEL   512
#define D_STATE   16
#define D_CONV    5
#define HEADDIM   64
#define D_INNER   1024
#define NHEADS    16
#define CONV_DIM  1056      // D_INNER + 2*D_STATE
#define D_IN_PROJ 2096      // 2*D_INNER + 2*D_STATE + NHEADS
#define B_SZ      16
#define SEQ       960
#define MROWS     (B_SZ*SEQ)   // 15360
#define EPS       1e-5f

// ---------------------------------------------------------------------------
// Generic fp32 tiled GEMM: C[m,n] = (accum ? C[m,n] : 0) + sum_k A[m,k]*B[k,n]
//                                   (+bias[n] if bias)
// A row-major (lda), B row-major (ldb), C row-major (ldc).
// Requires M % 128 == 0, K % 16 == 0 (true for all uses). N edge guarded.
// ---------------------------------------------------------------------------
#define BM 128
#define BN 128
#define BKK 16

__global__ __launch_bounds__(256) void gemm_f32(
    const float* __restrict__ A, const float* __restrict__ B,
    float* __restrict__ C, const float* __restrict__ bias,
    int N, int K, int lda, int ldb, int ldc, int accum)
{
  __shared__ float As[BKK][BM + 4];   // A stored transposed: As[k][m]
  __shared__ float Bs[BKK][BN + 4];

  const int tid = threadIdx.x;
  const int bm = blockIdx.x * BM;
  const int bn = blockIdx.y * BN;
  const int tx = tid & 15;        // col group
  const int ty = tid >> 4;        // row group

  // global-load mapping
  const int am = tid >> 2;              // 0..63  (A rows am, am+64)
  const int ak = (tid & 3) * 4;         // 0,4,8,12
  const int bk = tid >> 5;              // 0..7   (B rows bk, bk+8)
  const int bc = (tid & 31) * 4;        // 0..124

  float acc[8][8];
  #pragma unroll
  for (int i = 0; i < 8; ++i)
    #pragma unroll
    for (int j = 0; j < 8; ++j) acc[i][j] = 0.f;

  const int colb = bn + bc;
  const bool bok = (colb < N);

  for (int k0 = 0; k0 < K; k0 += BKK) {
    // stage A (transposed)
    float4 av0 = *(const float4*)&A[(size_t)(bm + am) * lda + k0 + ak];
    float4 av1 = *(const float4*)&A[(size_t)(bm + am + 64) * lda + k0 + ak];
    As[ak + 0][am]      = av0.x; As[ak + 1][am]      = av0.y;
    As[ak + 2][am]      = av0.z; As[ak + 3][am]      = av0.w;
    As[ak + 0][am + 64] = av1.x; As[ak + 1][am + 64] = av1.y;
    As[ak + 2][am + 64] = av1.z; As[ak + 3][am + 64] = av1.w;
    // stage B
    float4 z4 = make_float4(0.f, 0.f, 0.f, 0.f);
    float4 bv0 = bok ? *(const float4*)&B[(size_t)(k0 + bk) * ldb + colb]     : z4;
    float4 bv1 = bok ? *(const float4*)&B[(size_t)(k0 + bk + 8) * ldb + colb] : z4;
    *(float4*)&Bs[bk][bc]     = bv0;
    *(float4*)&Bs[bk + 8][bc] = bv1;
    __syncthreads();

    #pragma unroll
    for (int k = 0; k < BKK; ++k) {
      float4 a0 = *(const float4*)&As[k][ty * 4];
      float4 a1 = *(const float4*)&As[k][64 + ty * 4];
      float4 b0 = *(const float4*)&Bs[k][tx * 4];
      float4 b1 = *(const float4*)&Bs[k][64 + tx * 4];
      float a[8] = {a0.x, a0.y, a0.z, a0.w, a1.x, a1.y, a1.z, a1.w};
      float bb[8] = {b0.x, b0.y, b0.z, b0.w, b1.x, b1.y, b1.z, b1.w};
      #pragma unroll
      for (int i = 0; i < 8; ++i)
        #pragma unroll
        for (int j = 0; j < 8; ++j)
          acc[i][j] = __builtin_fmaf(a[i], bb[j], acc[i][j]);
    }
    __syncthreads();
  }

  // epilogue
  const int n0 = bn + tx * 4;
  const int n1 = bn + 64 + tx * 4;
  float4 bias0 = make_float4(0.f, 0.f, 0.f, 0.f), bias1 = bias0;
  if (bias) {
    if (n0 < N) bias0 = *(const float4*)&bias[n0];
    if (n1 < N) bias1 = *(const float4*)&bias[n1];
  }
  #pragma unroll
  for (int i = 0; i < 8; ++i) {
    int row = bm + ((i < 4) ? (ty * 4 + i) : (64 + ty * 4 + i - 4));
    if (n0 < N) {
      float4 v = make_float4(acc[i][0] + bias0.x, acc[i][1] + bias0.y,
                             acc[i][2] + bias0.z, acc[i][3] + bias0.w);
      if (accum) {
        float4 c = *(const float4*)&C[(size_t)row * ldc + n0];
        v.x += c.x; v.y += c.y; v.z += c.z; v.w += c.w;
      }
      *(float4*)&C[(size_t)row * ldc + n0] = v;
    }
    if (n1 < N) {
      float4 v = make_float4(acc[i][4] + bias1.x, acc[i][5] + bias1.y,
                             acc[i][6] + bias1.z, acc[i][7] + bias1.w);
      if (accum) {
        float4 c = *(const float4*)&C[(size_t)row * ldc + n1];
        v.x += c.x; v.y += c.y; v.z += c.z; v.w += c.w;
      }
      *(float4*)&C[(size_t)row * ldc + n1] = v;
    }
  }
}

// ---------------------------------------------------------------------------
// Depthwise causal (dir=0) / anti-causal (dir=1) conv over time + bias + silu.
// input = zbuf columns [1024, 2080); output (MROWS, 1056).
// dir==1 implements the flipped-conv-flipped composition in original coords:
//   out[l] = sum_j w[j] * in[l+4-j]
// ---------------------------------------------------------------------------
__global__ __launch_bounds__(256) void conv_silu(
    const float* __restrict__ zx, const float* __restrict__ cw,
    const float* __restrict__ cb, float* __restrict__ out, int dir)
{
  int idx = blockIdx.x * 256 + threadIdx.x;
  if (idx >= MROWS * CONV_DIM) return;
  int c  = idx % CONV_DIM;
  int bl = idx / CONV_DIM;
  int l  = bl % SEQ;
  int rowbase = bl - l;   // b*SEQ

  float acc = 0.f;
  #pragma unroll
  for (int j = 0; j < D_CONV; ++j) {
    int li = dir ? (l + 4 - j) : (l - 4 + j);
    if (li >= 0 && li < SEQ)
      acc = __builtin_fmaf(cw[c * D_CONV + j],
                           zx[(size_t)(rowbase + li) * D_IN_PROJ + D_INNER + c], acc);
  }
  float v = acc + cb[c];
  out[idx] = v / (1.f + __expf(-v));
}

// ---------------------------------------------------------------------------
// Selective scan, one direction. One wave per (b, head): 256 blocks x 64 thr.
// Lane p holds state h[p][0..16). Reads z/dt from zbuf, x/B/C from convbuf.
// Writes y_gated = (scan_y + D*x) * silu(z) into y (= zbuf cols [1024,2048),
// the dead xBC region; ld = D_IN_PROJ). Software-prefetches step t+1.
// ---------------------------------------------------------------------------
__global__ __launch_bounds__(64) void scan_kernel(
    const float* __restrict__ zx, const float* __restrict__ xc,
    const float* __restrict__ dtb_p, const float* __restrict__ Alog_p,
    const float* __restrict__ D_p, float* __restrict__ y, int dir)
{
  int b  = blockIdx.x >> 4;
  int hd = blockIdx.x & 15;

  float dtb = dtb_p[hd];
  float A   = -__expf(Alog_p[hd]);
  float Dv  = D_p[hd];

  int p = threadIdx.x;
  const float* xrow = xc + (size_t)b * SEQ * CONV_DIM;
  const float* zrow = zx + (size_t)b * SEQ * D_IN_PROJ;
  float*       yrow = y  + (size_t)b * SEQ * D_IN_PROJ + hd * 64 + p;

  float h[16];
  #pragma unroll
  for (int n = 0; n < 16; ++n) h[n] = 0.f;

  float xv, zv, dtr;
  float4 Bv[4], Cv[4];
#define LOADT(tt, XV, ZV, DTR, BV, CV) do {                                 \
    size_t xb = (size_t)(tt) * CONV_DIM;                                    \
    size_t zb = (size_t)(tt) * D_IN_PROJ;                                   \
    XV  = xrow[xb + hd * 64 + p];                                           \
    ZV  = zrow[zb + hd * 64 + p];                                           \
    DTR = zrow[zb + D_INNER + CONV_DIM + hd];                               \
    const float4* B4 = (const float4*)(xrow + xb + D_INNER);                \
    const float4* C4 = (const float4*)(xrow + xb + D_INNER + D_STATE);      \
    BV[0] = B4[0]; BV[1] = B4[1]; BV[2] = B4[2]; BV[3] = B4[3];             \
    CV[0] = C4[0]; CV[1] = C4[1]; CV[2] = C4[2]; CV[3] = C4[3];             \
  } while (0)

  int t0 = dir ? (SEQ - 1) : 0;
  LOADT(t0, xv, zv, dtr, Bv, Cv);

  for (int t = 0; t < SEQ; ++t) {
    int tt = dir ? (SEQ - 1 - t) : t;
    // prefetch next step
    float nxv = 0.f, nzv = 0.f, ndtr = 0.f;
    float4 nB[4], nC[4];
    if (t + 1 < SEQ) {
      int tn = dir ? (tt - 1) : (tt + 1);
      LOADT(tn, nxv, nzv, ndtr, nB, nC);
    }

    float dtrb = dtr + dtb;
    float dt = (dtrb > 20.f) ? dtrb : log1pf(__expf(dtrb));
    float dA = __expf(dt * A);
    float dtx = dt * xv;
    float yv = 0.f;
#define SCAN_STEP(n, Bc, Cc) \
    h[n] = __builtin_fmaf(h[n], dA, dtx * (Bc)); \
    yv = __builtin_fmaf(h[n], (Cc), yv);
    SCAN_STEP(0,  Bv[0].x, Cv[0].x) SCAN_STEP(1,  Bv[0].y, Cv[0].y)
    SCAN_STEP(2,  Bv[0].z, Cv[0].z) SCAN_STEP(3,  Bv[0].w, Cv[0].w)
    SCAN_STEP(4,  Bv[1].x, Cv[1].x) SCAN_STEP(5,  Bv[1].y, Cv[1].y)
    SCAN_STEP(6,  Bv[1].z, Cv[1].z) SCAN_STEP(7,  Bv[1].w, Cv[1].w)
    SCAN_STEP(8,  Bv[2].x, Cv[2].x) SCAN_STEP(9,  Bv[2].y, Cv[2].y)
    SCAN_STEP(10, Bv[2].z, Cv[2].z) SCAN_STEP(11, Bv[2].w, Cv[2].w)
    SCAN_STEP(12, Bv[3].x, Cv[3].x) SCAN_STEP(13, Bv[3].y, Cv[3].y)
    SCAN_STEP(14, Bv[3].z, Cv[3].z) SCAN_STEP(15, Bv[3].w, Cv[3].w)
#undef SCAN_STEP

    float sz = zv / (1.f + __expf(-zv));
    yrow[(size_t)tt * D_IN_PROJ] = (yv + Dv * xv) * sz;

    xv = nxv; zv = nzv; dtr = ndtr;
    #pragma unroll
    for (int q = 0; q < 4; ++q) { Bv[q] = nB[q]; Cv[q] = nC[q]; }
  }
#undef LOADT
}

// ---------------------------------------------------------------------------
// In-place gated RMSNorm over D_INNER=1024 with row stride ld.
// One block (256 thr) per row.
// ---------------------------------------------------------------------------
__device__ __forceinline__ float wave_sum64(float v) {
  #pragma unroll
  for (int off = 32; off; off >>= 1) v += __shfl_xor(v, off, 64);
  return v;
}

__global__ __launch_bounds__(256) void rmsnorm_kernel(
    float* __restrict__ y, const float* __restrict__ w, int ld)
{
  int row = blockIdx.x;
  float4* yp = (float4*)(y + (size_t)row * ld);
  int c = threadIdx.x;                      // 256 * 4 = 1024
  float4 v = yp[c];
  float ss = v.x * v.x + v.y * v.y + v.z * v.z + v.w * v.w;
  ss = wave_sum64(ss);
  __shared__ float part[4];
  if ((threadIdx.x & 63) == 0) part[threadIdx.x >> 6] = ss;
  __syncthreads();
  float tot = part[0] + part[1] + part[2] + part[3];
  float scale = rsqrtf(tot * (1.f / D_INNER) + EPS);
  float4 wv = ((const float4*)w)[c];
  v.x *= scale * wv.x; v.y *= scale * wv.y;
  v.z *= scale * wv.z; v.w *= scale * wv.w;
  yp[c] = v;
}

// ---------------------------------------------------------------------------
// Final: h = x + x_out ; LayerNorm(512) * g + b -> out.  (xo may alias out.)
// ---------------------------------------------------------------------------
__global__ __launch_bounds__(256) void ln_final(
    const float* __restrict__ x, const float* __restrict__ xo,
    const float* __restrict__ g, const float* __restrict__ bb,
    float* __restrict__ out)
{
  int row = blockIdx.x;
  int c = threadIdx.x;                      // 256 * 2 = 512
  float2 xv = ((const float2*)(x  + (size_t)row * D_MODEL))[c];
  float2 ov = ((const float2*)(xo + (size_t)row * D_MODEL))[c];
  float hx = xv.x + ov.x, hy = xv.y + ov.y;
  float s  = hx + hy;
  float sq = hx * hx + hy * hy;
  s  = wave_sum64(s);
  sq = wave_sum64(sq);
  __shared__ float ps[4], pq[4];
  if ((threadIdx.x & 63) == 0) { ps[threadIdx.x >> 6] = s; pq[threadIdx.x >> 6] = sq; }
  __syncthreads();
  float tots = ps[0] + ps[1] + ps[2] + ps[3];
  float totq = pq[0] + pq[1] + pq[2] + pq[3];
  float mu  = tots * (1.f / D_MODEL);
  float var = totq * (1.f / D_MODEL) - mu * mu;
  float inv = rsqrtf(var + EPS);
  float2 gv = ((const float2*)g)[c];
  float2 bv = ((const float2*)bb)[c];
  float2 o;
  o.x = (hx - mu) * inv * gv.x + bv.x;
  o.y = (hy - mu) * inv * gv.y + bv.y;
  ((float2*)(out + (size_t)row * D_MODEL))[c] = o;
}

// ---------------------------------------------------------------------------
extern "C" void kernel_launch(void* const* d_in, const int* in_sizes, int n_in,
                              void* d_out, int out_size, void* d_ws, size_t ws_size,
                              hipStream_t stream) {
  const float* x      = (const float*)d_in[0];
  const float* proj_W = (const float*)d_in[17];
  const float* proj_b = (const float*)d_in[18];
  const float* ln_g   = (const float*)d_in[19];
  const float* ln_b   = (const float*)d_in[20];
  float* out = (float*)d_out;

  // Workspace layout (sequential per-direction; 187 MiB total):
  //   zbuf    (MROWS, 2096)  in_proj out; scan writes y into cols [1024,2048)
  //   convbuf (MROWS, 1056)  conv+silu out
  //   Wcomb   (1024, 512)    W_out @ proj_W_half for current direction
  const size_t SZ_Z = (size_t)MROWS * D_IN_PROJ;   // 32,194,560
  const size_t SZ_C = (size_t)MROWS * CONV_DIM;    // 16,220,160
  const size_t SZ_W = (size_t)D_INNER * D_MODEL;   //    524,288
  const size_t NEED = (SZ_Z + SZ_C + SZ_W) * sizeof(float);  // 195,756,032 B
  if (ws_size < NEED) {
    // Diagnostic fallback: wrong-but-finite output instead of a page fault.
    hipMemsetAsync(d_out, 0, (size_t)out_size * sizeof(float), stream);
    return;
  }
  float* zbuf    = (float*)d_ws;
  float* convbuf = zbuf + SZ_Z;
  float* Wcomb   = convbuf + SZ_C;
  float* ybuf    = zbuf + D_INNER;   // y at ld = D_IN_PROJ over dead xBC cols

  dim3 blk(256);

  for (int dir = 0; dir < 2; ++dir) {
    const float* W_in    = (const float*)d_in[dir ? 9  : 1];
    const float* conv_w  = (const float*)d_in[dir ? 10 : 2];
    const float* conv_b  = (const float*)d_in[dir ? 11 : 3];
    const float* dt_bias = (const float*)d_in[dir ? 12 : 4];
    const float* A_log   = (const float*)d_in[dir ? 13 : 5];
    const float* Dp      = (const float*)d_in[dir ? 14 : 6];
    const float* norm_w  = (const float*)d_in[dir ? 15 : 7];
    const float* W_out   = (const float*)d_in[dir ? 16 : 8];

    // 1. in_proj: (15360,512)@(512,2096) -> zbuf
    {
      dim3 grid(MROWS / BM, (D_IN_PROJ + BN - 1) / BN);
      gemm_f32<<<grid, blk, 0, stream>>>(x, W_in, zbuf, nullptr,
                                         D_IN_PROJ, D_MODEL, D_MODEL, D_IN_PROJ,
                                         D_IN_PROJ, 0);
    }
    // 2. conv + silu -> convbuf
    {
      dim3 grid((MROWS * CONV_DIM + 255) / 256);
      conv_silu<<<grid, blk, 0, stream>>>(zbuf, conv_w, conv_b, convbuf, dir);
    }
    // 3. scan -> ybuf (over zbuf's dead xBC columns)
    scan_kernel<<<dim3(256), dim3(64), 0, stream>>>(
        zbuf, convbuf, dt_bias, A_log, Dp, ybuf, dir);
    // 4. gated RMSNorm in place (ld = 2096)
    rmsnorm_kernel<<<dim3(MROWS), blk, 0, stream>>>(ybuf, norm_w, D_IN_PROJ);
    // 5. Wcomb = W_out @ proj_W[dir half]  (1024x512 @ 512x512)
    {
      dim3 grid(D_INNER / BM, (D_MODEL + BN - 1) / BN);
      gemm_f32<<<grid, blk, 0, stream>>>(
          W_out, proj_W + (size_t)dir * D_MODEL * D_MODEL, Wcomb, nullptr,
          D_MODEL, D_MODEL, D_MODEL, D_MODEL, D_MODEL, 0);
    }
    // 6. out accumulate: d_out (+)= y @ Wcomb (+ proj_b on dir 0)
    {
      dim3 grid(MROWS / BM, (D_MODEL + BN - 1) / BN);
      gemm_f32<<<grid, blk, 0, stream>>>(ybuf, Wcomb, out,
                                         dir ? nullptr : proj_b,
                                         D_MODEL, D_INNER, D_IN_PROJ, D_MODEL,
                                         D_MODEL, dir);
    }
  }

  // 7. residual + LayerNorm (xo aliases out; per-thread read-then-write)
  ln_final<<<dim3(MROWS), blk, 0, stream>>>(x, out, ln_g, ln_b, out);
}

// Round 6
// 2152.124 us; speedup vs baseline: 1.3245x; 1.3245x over previous
//
#include <hip/hip_runtime.h>
#include <hip/hip_bf16.h>

#define D_MODEL   512
#define D_STATE   16
#define D_CONV    5
#define HEADDIM   64
#define D_INNER   1024
#define NHEADS    16
#define CONV_DIM  1056      // D_INNER + 2*D_STATE
#define D_IN_PROJ 2096      // 2*D_INNER + 2*D_STATE + NHEADS
#define B_SZ      16
#define SEQ       960
#define MROWS     (B_SZ*SEQ)   // 15360
#define EPS       1e-5f
#define NCHUNK    6
#define CLEN      160          // SEQ / NCHUNK

// ---------------------------------------------------------------------------
// Generic fp32 tiled GEMM: C[m,n] = (accum ? C[m,n] : 0) + sum_k A[m,k]*B[k,n]
//                                   (+bias[n] if bias)
// ---------------------------------------------------------------------------
#define BM 128
#define BN 128
#define BKK 16

__global__ __launch_bounds__(256) void gemm_f32(
    const float* __restrict__ A, const float* __restrict__ B,
    float* __restrict__ C, const float* __restrict__ bias,
    int N, int K, int lda, int ldb, int ldc, int accum)
{
  __shared__ float As[BKK][BM + 4];   // A stored transposed: As[k][m]
  __shared__ float Bs[BKK][BN + 4];

  const int tid = threadIdx.x;
  const int bm = blockIdx.x * BM;
  const int bn = blockIdx.y * BN;
  const int tx = tid & 15;        // col group
  const int ty = tid >> 4;        // row group

  const int am = tid >> 2;              // 0..63  (A rows am, am+64)
  const int ak = (tid & 3) * 4;         // 0,4,8,12
  const int bk = tid >> 5;              // 0..7   (B rows bk, bk+8)
  const int bc = (tid & 31) * 4;        // 0..124

  float acc[8][8];
  #pragma unroll
  for (int i = 0; i < 8; ++i)
    #pragma unroll
    for (int j = 0; j < 8; ++j) acc[i][j] = 0.f;

  const int colb = bn + bc;
  const bool bok = (colb < N);

  for (int k0 = 0; k0 < K; k0 += BKK) {
    float4 av0 = *(const float4*)&A[(size_t)(bm + am) * lda + k0 + ak];
    float4 av1 = *(const float4*)&A[(size_t)(bm + am + 64) * lda + k0 + ak];
    As[ak + 0][am]      = av0.x; As[ak + 1][am]      = av0.y;
    As[ak + 2][am]      = av0.z; As[ak + 3][am]      = av0.w;
    As[ak + 0][am + 64] = av1.x; As[ak + 1][am + 64] = av1.y;
    As[ak + 2][am + 64] = av1.z; As[ak + 3][am + 64] = av1.w;
    float4 z4 = make_float4(0.f, 0.f, 0.f, 0.f);
    float4 bv0 = bok ? *(const float4*)&B[(size_t)(k0 + bk) * ldb + colb]     : z4;
    float4 bv1 = bok ? *(const float4*)&B[(size_t)(k0 + bk + 8) * ldb + colb] : z4;
    *(float4*)&Bs[bk][bc]     = bv0;
    *(float4*)&Bs[bk + 8][bc] = bv1;
    __syncthreads();

    #pragma unroll
    for (int k = 0; k < BKK; ++k) {
      float4 a0 = *(const float4*)&As[k][ty * 4];
      float4 a1 = *(const float4*)&As[k][64 + ty * 4];
      float4 b0 = *(const float4*)&Bs[k][tx * 4];
      float4 b1 = *(const float4*)&Bs[k][64 + tx * 4];
      float a[8] = {a0.x, a0.y, a0.z, a0.w, a1.x, a1.y, a1.z, a1.w};
      float bb[8] = {b0.x, b0.y, b0.z, b0.w, b1.x, b1.y, b1.z, b1.w};
      #pragma unroll
      for (int i = 0; i < 8; ++i)
        #pragma unroll
        for (int j = 0; j < 8; ++j)
          acc[i][j] = __builtin_fmaf(a[i], bb[j], acc[i][j]);
    }
    __syncthreads();
  }

  const int n0 = bn + tx * 4;
  const int n1 = bn + 64 + tx * 4;
  float4 bias0 = make_float4(0.f, 0.f, 0.f, 0.f), bias1 = bias0;
  if (bias) {
    if (n0 < N) bias0 = *(const float4*)&bias[n0];
    if (n1 < N) bias1 = *(const float4*)&bias[n1];
  }
  #pragma unroll
  for (int i = 0; i < 8; ++i) {
    int row = bm + ((i < 4) ? (ty * 4 + i) : (64 + ty * 4 + i - 4));
    if (n0 < N) {
      float4 v = make_float4(acc[i][0] + bias0.x, acc[i][1] + bias0.y,
                             acc[i][2] + bias0.z, acc[i][3] + bias0.w);
      if (accum) {
        float4 c = *(const float4*)&C[(size_t)row * ldc + n0];
        v.x += c.x; v.y += c.y; v.z += c.z; v.w += c.w;
      }
      *(float4*)&C[(size_t)row * ldc + n0] = v;
    }
    if (n1 < N) {
      float4 v = make_float4(acc[i][4] + bias1.x, acc[i][5] + bias1.y,
                             acc[i][6] + bias1.z, acc[i][7] + bias1.w);
      if (accum) {
        float4 c = *(const float4*)&C[(size_t)row * ldc + n1];
        v.x += c.x; v.y += c.y; v.z += c.z; v.w += c.w;
      }
      *(float4*)&C[(size_t)row * ldc + n1] = v;
    }
  }
}

// ---------------------------------------------------------------------------
// Depthwise causal (dir=0) / anti-causal (dir=1) conv + bias + silu.
// ---------------------------------------------------------------------------
__global__ __launch_bounds__(256) void conv_silu(
    const float* __restrict__ zx, const float* __restrict__ cw,
    const float* __restrict__ cb, float* __restrict__ out, int dir)
{
  int idx = blockIdx.x * 256 + threadIdx.x;
  if (idx >= MROWS * CONV_DIM) return;
  int c  = idx % CONV_DIM;
  int bl = idx / CONV_DIM;
  int l  = bl % SEQ;
  int rowbase = bl - l;   // b*SEQ

  float acc = 0.f;
  #pragma unroll
  for (int j = 0; j < D_CONV; ++j) {
    int li = dir ? (l + 4 - j) : (l - 4 + j);
    if (li >= 0 && li < SEQ)
      acc = __builtin_fmaf(cw[c * D_CONV + j],
                           zx[(size_t)(rowbase + li) * D_IN_PROJ + D_INNER + c], acc);
  }
  float v = acc + cb[c];
  out[idx] = v / (1.f + __expf(-v));
}

// ---------------------------------------------------------------------------
// Chunked selective scan (SSD decomposition).  dA_t is scalar per head, so
// over a chunk: h_end = (prod dA)*h_start + h_local(0-init).
// Logical step s = 0..959 maps to physical tt = dir ? 959-s : s.
// Chunk c covers s in [c*CLEN, (c+1)*CLEN).
//
// pass1: per (b,hd,chunk) wave, compute h_local + P = prod(dA); store.
// combine: per (b,hd) wave, 6-step serial rewrite: states <- chunk h0.
// pass3: per (b,hd,chunk) wave, re-run chunk from h0, emit gated y.
// ---------------------------------------------------------------------------
__global__ __launch_bounds__(64) void scan_pass1(
    const float* __restrict__ zx, const float* __restrict__ xc,
    const float* __restrict__ dtb_p, const float* __restrict__ Alog_p,
    float* __restrict__ states, float* __restrict__ Pbuf, int dir)
{
  int blk = blockIdx.x;
  int c   = blk % NCHUNK;
  int bh  = blk / NCHUNK;
  int b = bh >> 4, hd = bh & 15;
  float dtb = dtb_p[hd];
  float A   = -__expf(Alog_p[hd]);
  int p = threadIdx.x;
  const float* xrow = xc + (size_t)b * SEQ * CONV_DIM;
  const float* zrow = zx + (size_t)b * SEQ * D_IN_PROJ;

  float h[16];
  #pragma unroll
  for (int n = 0; n < 16; ++n) h[n] = 0.f;
  float P = 1.f;

  const int s0 = c * CLEN, s1 = s0 + CLEN;

  float xv0, dtr0; float4 B0[4];
  float xv1, dtr1; float4 B1[4];

#define P1LOAD(ss, XV, DTR, BB) do {                                        \
    int tt_ = dir ? (SEQ - 1 - (ss)) : (ss);                                \
    size_t xb_ = (size_t)tt_ * CONV_DIM;                                    \
    XV  = xrow[xb_ + hd * 64 + p];                                          \
    DTR = zrow[(size_t)tt_ * D_IN_PROJ + (D_INNER + CONV_DIM) + hd];        \
    const float4* B4_ = (const float4*)(xrow + xb_ + D_INNER);              \
    BB[0] = B4_[0]; BB[1] = B4_[1]; BB[2] = B4_[2]; BB[3] = B4_[3];         \
  } while (0)

  P1LOAD(s0, xv0, dtr0, B0);
  P1LOAD(s0 + 1, xv1, dtr1, B1);

  #pragma unroll 4
  for (int s = s0; s < s1; ++s) {
    float dtrb = dtr0 + dtb;
    float dt = (dtrb > 20.f) ? dtrb : log1pf(__expf(dtrb));
    float dA = __expf(dt * A);
    P *= dA;
    float dtx = dt * xv0;
#define ST1(n, Bc) h[n] = __builtin_fmaf(h[n], dA, dtx * (Bc));
    ST1(0,  B0[0].x) ST1(1,  B0[0].y) ST1(2,  B0[0].z) ST1(3,  B0[0].w)
    ST1(4,  B0[1].x) ST1(5,  B0[1].y) ST1(6,  B0[1].z) ST1(7,  B0[1].w)
    ST1(8,  B0[2].x) ST1(9,  B0[2].y) ST1(10, B0[2].z) ST1(11, B0[2].w)
    ST1(12, B0[3].x) ST1(13, B0[3].y) ST1(14, B0[3].z) ST1(15, B0[3].w)
#undef ST1
    // rotate prefetch buffers; fetch s+2 (clamped inside chunk)
    xv0 = xv1; dtr0 = dtr1;
    #pragma unroll
    for (int q = 0; q < 4; ++q) B0[q] = B1[q];
    int sn = s + 2; if (sn > s1 - 1) sn = s1 - 1;
    P1LOAD(sn, xv1, dtr1, B1);
  }
#undef P1LOAD

  float4* sp = (float4*)&states[(((size_t)bh * NCHUNK + c) * 64 + p) * 16];
  sp[0] = make_float4(h[0],  h[1],  h[2],  h[3]);
  sp[1] = make_float4(h[4],  h[5],  h[6],  h[7]);
  sp[2] = make_float4(h[8],  h[9],  h[10], h[11]);
  sp[3] = make_float4(h[12], h[13], h[14], h[15]);
  if (p == 0) Pbuf[bh * NCHUNK + c] = P;
}

__global__ __launch_bounds__(64) void scan_combine(
    float* __restrict__ states, const float* __restrict__ Pbuf)
{
  int bh = blockIdx.x;
  int p  = threadIdx.x;
  float4 h0 = make_float4(0,0,0,0), h1 = h0, h2 = h0, h3 = h0;
  for (int c = 0; c < NCHUNK; ++c) {
    float4* sp = (float4*)&states[(((size_t)bh * NCHUNK + c) * 64 + p) * 16];
    float P = Pbuf[bh * NCHUNK + c];
    float4 s0 = sp[0], s1 = sp[1], s2 = sp[2], s3 = sp[3];
    sp[0] = h0; sp[1] = h1; sp[2] = h2; sp[3] = h3;   // chunk-initial state
    h0.x = __builtin_fmaf(P, h0.x, s0.x); h0.y = __builtin_fmaf(P, h0.y, s0.y);
    h0.z = __builtin_fmaf(P, h0.z, s0.z); h0.w = __builtin_fmaf(P, h0.w, s0.w);
    h1.x = __builtin_fmaf(P, h1.x, s1.x); h1.y = __builtin_fmaf(P, h1.y, s1.y);
    h1.z = __builtin_fmaf(P, h1.z, s1.z); h1.w = __builtin_fmaf(P, h1.w, s1.w);
    h2.x = __builtin_fmaf(P, h2.x, s2.x); h2.y = __builtin_fmaf(P, h2.y, s2.y);
    h2.z = __builtin_fmaf(P, h2.z, s2.z); h2.w = __builtin_fmaf(P, h2.w, s2.w);
    h3.x = __builtin_fmaf(P, h3.x, s3.x); h3.y = __builtin_fmaf(P, h3.y, s3.y);
    h3.z = __builtin_fmaf(P, h3.z, s3.z); h3.w = __builtin_fmaf(P, h3.w, s3.w);
  }
}

__global__ __launch_bounds__(64) void scan_pass3(
    const float* __restrict__ zx, const float* __restrict__ xc,
    const float* __restrict__ dtb_p, const float* __restrict__ Alog_p,
    const float* __restrict__ D_p, const float* __restrict__ states,
    float* __restrict__ y, int dir)
{
  int blk = blockIdx.x;
  int c   = blk % NCHUNK;
  int bh  = blk / NCHUNK;
  int b = bh >> 4, hd = bh & 15;
  float dtb = dtb_p[hd];
  float A   = -__expf(Alog_p[hd]);
  float Dv  = D_p[hd];
  int p = threadIdx.x;
  const float* xrow = xc + (size_t)b * SEQ * CONV_DIM;
  const float* zrow = zx + (size_t)b * SEQ * D_IN_PROJ;
  float*       yrow = y  + (size_t)b * SEQ * D_IN_PROJ + hd * 64 + p;

  float h[16];
  {
    const float4* sp =
        (const float4*)&states[(((size_t)bh * NCHUNK + c) * 64 + p) * 16];
    float4 s0 = sp[0], s1 = sp[1], s2 = sp[2], s3 = sp[3];
    h[0]=s0.x; h[1]=s0.y; h[2]=s0.z; h[3]=s0.w;
    h[4]=s1.x; h[5]=s1.y; h[6]=s1.z; h[7]=s1.w;
    h[8]=s2.x; h[9]=s2.y; h[10]=s2.z; h[11]=s2.w;
    h[12]=s3.x; h[13]=s3.y; h[14]=s3.z; h[15]=s3.w;
  }

  const int s0i = c * CLEN, s1i = s0i + CLEN;

  float xv0, zv0, dtr0; float4 B0[4], C0[4];
  float xv1, zv1, dtr1; float4 B1[4], C1[4];

#define P3LOAD(ss, XV, ZV, DTR, BB, CC) do {                                \
    int tt_ = dir ? (SEQ - 1 - (ss)) : (ss);                                \
    size_t xb_ = (size_t)tt_ * CONV_DIM;                                    \
    size_t zb_ = (size_t)tt_ * D_IN_PROJ;                                   \
    XV  = xrow[xb_ + hd * 64 + p];                                          \
    ZV  = zrow[zb_ + hd * 64 + p];                                          \
    DTR = zrow[zb_ + (D_INNER + CONV_DIM) + hd];                            \
    const float4* B4_ = (const float4*)(xrow + xb_ + D_INNER);              \
    const float4* C4_ = (const float4*)(xrow + xb_ + D_INNER + D_STATE);    \
    BB[0] = B4_[0]; BB[1] = B4_[1]; BB[2] = B4_[2]; BB[3] = B4_[3];         \
    CC[0] = C4_[0]; CC[1] = C4_[1]; CC[2] = C4_[2]; CC[3] = C4_[3];         \
  } while (0)

  P3LOAD(s0i, xv0, zv0, dtr0, B0, C0);
  P3LOAD(s0i + 1, xv1, zv1, dtr1, B1, C1);

  #pragma unroll 4
  for (int s = s0i; s < s1i; ++s) {
    int tt = dir ? (SEQ - 1 - s) : s;
    float dtrb = dtr0 + dtb;
    float dt = (dtrb > 20.f) ? dtrb : log1pf(__expf(dtrb));
    float dA = __expf(dt * A);
    float dtx = dt * xv0;
    float yv = 0.f;
#define ST3(n, Bc, Cc) \
    h[n] = __builtin_fmaf(h[n], dA, dtx * (Bc)); \
    yv = __builtin_fmaf(h[n], (Cc), yv);
    ST3(0,  B0[0].x, C0[0].x) ST3(1,  B0[0].y, C0[0].y)
    ST3(2,  B0[0].z, C0[0].z) ST3(3,  B0[0].w, C0[0].w)
    ST3(4,  B0[1].x, C0[1].x) ST3(5,  B0[1].y, C0[1].y)
    ST3(6,  B0[1].z, C0[1].z) ST3(7,  B0[1].w, C0[1].w)
    ST3(8,  B0[2].x, C0[2].x) ST3(9,  B0[2].y, C0[2].y)
    ST3(10, B0[2].z, C0[2].z) ST3(11, B0[2].w, C0[2].w)
    ST3(12, B0[3].x, C0[3].x) ST3(13, B0[3].y, C0[3].y)
    ST3(14, B0[3].z, C0[3].z) ST3(15, B0[3].w, C0[3].w)
#undef ST3

    float sz = zv0 / (1.f + __expf(-zv0));
    yrow[(size_t)tt * D_IN_PROJ] = (yv + Dv * xv0) * sz;

    xv0 = xv1; zv0 = zv1; dtr0 = dtr1;
    #pragma unroll
    for (int q = 0; q < 4; ++q) { B0[q] = B1[q]; C0[q] = C1[q]; }
    int sn = s + 2; if (sn > s1i - 1) sn = s1i - 1;
    P3LOAD(sn, xv1, zv1, dtr1, B1, C1);
  }
#undef P3LOAD
}

// ---------------------------------------------------------------------------
// In-place gated RMSNorm over D_INNER=1024 with row stride ld.
// ---------------------------------------------------------------------------
__device__ __forceinline__ float wave_sum64(float v) {
  #pragma unroll
  for (int off = 32; off; off >>= 1) v += __shfl_xor(v, off, 64);
  return v;
}

__global__ __launch_bounds__(256) void rmsnorm_kernel(
    float* __restrict__ y, const float* __restrict__ w, int ld)
{
  int row = blockIdx.x;
  float4* yp = (float4*)(y + (size_t)row * ld);
  int c = threadIdx.x;                      // 256 * 4 = 1024
  float4 v = yp[c];
  float ss = v.x * v.x + v.y * v.y + v.z * v.z + v.w * v.w;
  ss = wave_sum64(ss);
  __shared__ float part[4];
  if ((threadIdx.x & 63) == 0) part[threadIdx.x >> 6] = ss;
  __syncthreads();
  float tot = part[0] + part[1] + part[2] + part[3];
  float scale = rsqrtf(tot * (1.f / D_INNER) + EPS);
  float4 wv = ((const float4*)w)[c];
  v.x *= scale * wv.x; v.y *= scale * wv.y;
  v.z *= scale * wv.z; v.w *= scale * wv.w;
  yp[c] = v;
}

// ---------------------------------------------------------------------------
// Final: h = x + x_out ; LayerNorm(512) * g + b -> out.  (xo may alias out.)
// ---------------------------------------------------------------------------
__global__ __launch_bounds__(256) void ln_final(
    const float* __restrict__ x, const float* __restrict__ xo,
    const float* __restrict__ g, const float* __restrict__ bb,
    float* __restrict__ out)
{
  int row = blockIdx.x;
  int c = threadIdx.x;                      // 256 * 2 = 512
  float2 xv = ((const float2*)(x  + (size_t)row * D_MODEL))[c];
  float2 ov = ((const float2*)(xo + (size_t)row * D_MODEL))[c];
  float hx = xv.x + ov.x, hy = xv.y + ov.y;
  float s  = hx + hy;
  float sq = hx * hx + hy * hy;
  s  = wave_sum64(s);
  sq = wave_sum64(sq);
  __shared__ float ps[4], pq[4];
  if ((threadIdx.x & 63) == 0) { ps[threadIdx.x >> 6] = s; pq[threadIdx.x >> 6] = sq; }
  __syncthreads();
  float tots = ps[0] + ps[1] + ps[2] + ps[3];
  float totq = pq[0] + pq[1] + pq[2] + pq[3];
  float mu  = tots * (1.f / D_MODEL);
  float var = totq * (1.f / D_MODEL) - mu * mu;
  float inv = rsqrtf(var + EPS);
  float2 gv = ((const float2*)g)[c];
  float2 bv = ((const float2*)bb)[c];
  float2 o;
  o.x = (hx - mu) * inv * gv.x + bv.x;
  o.y = (hy - mu) * inv * gv.y + bv.y;
  ((float2*)(out + (size_t)row * D_MODEL))[c] = o;
}

// ---------------------------------------------------------------------------
extern "C" void kernel_launch(void* const* d_in, const int* in_sizes, int n_in,
                              void* d_out, int out_size, void* d_ws, size_t ws_size,
                              hipStream_t stream) {
  const float* x      = (const float*)d_in[0];
  const float* proj_W = (const float*)d_in[17];
  const float* proj_b = (const float*)d_in[18];
  const float* ln_g   = (const float*)d_in[19];
  const float* ln_b   = (const float*)d_in[20];
  float* out = (float*)d_out;

  // Workspace (sequential per-direction; ~190.7 MiB):
  //   zbuf    (MROWS, 2096)  in_proj out; scan y -> cols [1024,2048)
  //   convbuf (MROWS, 1056)  conv+silu out
  //   shared region: scan states+P (live during scan) / Wcomb (live after)
  const size_t SZ_Z  = (size_t)MROWS * D_IN_PROJ;        // 32,194,560
  const size_t SZ_C  = (size_t)MROWS * CONV_DIM;         // 16,220,160
  const size_t SZ_W  = (size_t)D_INNER * D_MODEL;        //    524,288
  const size_t SZ_ST = (size_t)256 * NCHUNK * 64 * 16;   //  1,572,864
  const size_t SZ_P  = (size_t)256 * NCHUNK;             //      1,536
  const size_t SZ_SH = (SZ_ST + SZ_P > SZ_W) ? (SZ_ST + SZ_P) : SZ_W;
  const size_t NEED  = (SZ_Z + SZ_C + SZ_SH) * sizeof(float);  // ~199.96 MB
  if (ws_size < NEED) {
    hipMemsetAsync(d_out, 0, (size_t)out_size * sizeof(float), stream);
    return;
  }
  float* zbuf    = (float*)d_ws;
  float* convbuf = zbuf + SZ_Z;
  float* shared  = convbuf + SZ_C;
  float* states  = shared;            // scan-time
  float* Pbuf    = shared + SZ_ST;    // scan-time
  float* Wcomb   = shared;            // post-scan (overlays states)
  float* ybuf    = zbuf + D_INNER;    // y at ld = D_IN_PROJ over dead xBC cols

  dim3 blk(256);

  for (int dir = 0; dir < 2; ++dir) {
    const float* W_in    = (const float*)d_in[dir ? 9  : 1];
    const float* conv_w  = (const float*)d_in[dir ? 10 : 2];
    const float* conv_b  = (const float*)d_in[dir ? 11 : 3];
    const float* dt_bias = (const float*)d_in[dir ? 12 : 4];
    const float* A_log   = (const float*)d_in[dir ? 13 : 5];
    const float* Dp      = (const float*)d_in[dir ? 14 : 6];
    const float* norm_w  = (const float*)d_in[dir ? 15 : 7];
    const float* W_out   = (const float*)d_in[dir ? 16 : 8];

    // 1. in_proj: (15360,512)@(512,2096) -> zbuf
    {
      dim3 grid(MROWS / BM, (D_IN_PROJ + BN - 1) / BN);
      gemm_f32<<<grid, blk, 0, stream>>>(x, W_in, zbuf, nullptr,
                                         D_IN_PROJ, D_MODEL, D_MODEL, D_IN_PROJ,
                                         D_IN_PROJ, 0);
    }
    // 2. conv + silu -> convbuf
    {
      dim3 grid((MROWS * CONV_DIM + 255) / 256);
      conv_silu<<<grid, blk, 0, stream>>>(zbuf, conv_w, conv_b, convbuf, dir);
    }
    // 3. chunked scan -> ybuf
    scan_pass1<<<dim3(256 * NCHUNK), dim3(64), 0, stream>>>(
        zbuf, convbuf, dt_bias, A_log, states, Pbuf, dir);
    scan_combine<<<dim3(256), dim3(64), 0, stream>>>(states, Pbuf);
    scan_pass3<<<dim3(256 * NCHUNK), dim3(64), 0, stream>>>(
        zbuf, convbuf, dt_bias, A_log, Dp, states, ybuf, dir);
    // 4. gated RMSNorm in place (ld = 2096)
    rmsnorm_kernel<<<dim3(MROWS), blk, 0, stream>>>(ybuf, norm_w, D_IN_PROJ);
    // 5. Wcomb = W_out @ proj_W[dir half]  (1024x512 @ 512x512)
    {
      dim3 grid(D_INNER / BM, (D_MODEL + BN - 1) / BN);
      gemm_f32<<<grid, blk, 0, stream>>>(
          W_out, proj_W + (size_t)dir * D_MODEL * D_MODEL, Wcomb, nullptr,
          D_MODEL, D_MODEL, D_MODEL, D_MODEL, D_MODEL, 0);
    }
    // 6. out accumulate: d_out (+)= y @ Wcomb (+ proj_b on dir 0)
    {
      dim3 grid(MROWS / BM, (D_MODEL + BN - 1) / BN);
      gemm_f32<<<grid, blk, 0, stream>>>(ybuf, Wcomb, out,
                                         dir ? nullptr : proj_b,
                                         D_MODEL, D_INNER, D_IN_PROJ, D_MODEL,
                                         D_MODEL, dir);
    }
  }

  // 7. residual + LayerNorm (xo aliases out; per-thread read-then-write)
  ln_final<<<dim3(MROWS), blk, 0, stream>>>(x, out, ln_g, ln_b, out);
}

// Round 7
// 1349.816 us; speedup vs baseline: 2.1117x; 1.5944x over previous
//
#include <hip/hip_runtime.h>
#include <hip/hip_bf16.h>

#define D_MODEL   512
#define D_STATE   16
#define D_CONV    5
#define HEADDIM   64
#define D_INNER   1024
#define NHEADS    16
#define CONV_DIM  1056      // D_INNER + 2*D_STATE
#define D_IN_PROJ 2096      // 2*D_INNER + 2*D_STATE + NHEADS
#define B_SZ      16
#define SEQ       960
#define MROWS     (B_SZ*SEQ)   // 15360
#define EPS       1e-5f
#define NCHUNK    6
#define CLEN      160          // SEQ / NCHUNK

typedef __attribute__((ext_vector_type(8))) short   short8;
typedef __attribute__((ext_vector_type(8))) ushort  u16x8;
typedef __attribute__((ext_vector_type(4))) float   f32x4;

// ---------------------------------------------------------------------------
// split-bf16 helpers: v ~= hi + lo (each bf16, RNE), rel err ~2^-17
// ---------------------------------------------------------------------------
__device__ __forceinline__ ushort bf16_rne(float f) {
  union { float f; unsigned u; } x; x.f = f;
  unsigned u = x.u;
  return (ushort)((u + 0x7FFFu + ((u >> 16) & 1u)) >> 16);
}
__device__ __forceinline__ float bf16_f(ushort h) {
  union { unsigned u; float f; } x; x.u = ((unsigned)h) << 16;
  return x.f;
}
__device__ __forceinline__ void cvt_split(float v, ushort& h, ushort& l) {
  h = bf16_rne(v);
  l = bf16_rne(v - bf16_f(h));
}

// ---------------------------------------------------------------------------
// Split-bf16 MFMA GEMM: C[m,n] = (accum?C:0) + A[m,:]·B[:,n] (+bias[n])
// A: M x K fp32 (lda). Bt: N x K fp32 (ldb) = B transposed. C: M x N (ldc).
// M % 128 == 0, K % 32 == 0. N edge guarded. Tile 128x128xBK32, 4 waves.
// 3-term split accumulation: AhBh + AhBl + AlBh (AlBl ~2^-18, dropped).
// ---------------------------------------------------------------------------
#define LDK 40   // padded k-stride (bf16 elems): 80B rows -> conflict-free b128

__global__ __launch_bounds__(256) void gemm_mfma(
    const float* __restrict__ A, const float* __restrict__ Bt,
    float* __restrict__ C, const float* __restrict__ bias,
    int M, int N, int K, int lda, int ldb, int ldc, int accum)
{
  __shared__ ushort As_hi[128][LDK], As_lo[128][LDK];
  __shared__ ushort Bs_hi[128][LDK], Bs_lo[128][LDK];

  const int tid  = threadIdx.x;
  const int lane = tid & 63;
  const int wave = tid >> 6;        // 4 waves, 2x2
  const int wm   = wave >> 1;
  const int wn   = wave & 1;
  const int brow = blockIdx.x * 128;
  const int bcol = blockIdx.y * 128;

  const int sr = tid >> 1;          // staged row 0..127
  const int sq = (tid & 1) * 16;    // k offset 0/16

  f32x4 acc[4][4];
  #pragma unroll
  for (int i = 0; i < 4; ++i)
    #pragma unroll
    for (int j = 0; j < 4; ++j) acc[i][j] = f32x4{0.f, 0.f, 0.f, 0.f};

  const int fr = lane & 15;
  const int fk = (lane >> 4) * 8;

#define CS(F, HV, LV, I) { ushort th_, tl_; cvt_split((F), th_, tl_); HV[I] = th_; LV[I] = tl_; }

  for (int k0 = 0; k0 < K; k0 += 32) {
    // ---- stage A (always valid: M % 128 == 0, K % 32 == 0)
    {
      const float* s = &A[(size_t)(brow + sr) * lda + k0 + sq];
      float4 a0 = *(const float4*)(s);
      float4 a1 = *(const float4*)(s + 4);
      float4 a2 = *(const float4*)(s + 8);
      float4 a3 = *(const float4*)(s + 12);
      u16x8 h0, h1, l0, l1;
      CS(a0.x, h0, l0, 0) CS(a0.y, h0, l0, 1) CS(a0.z, h0, l0, 2) CS(a0.w, h0, l0, 3)
      CS(a1.x, h0, l0, 4) CS(a1.y, h0, l0, 5) CS(a1.z, h0, l0, 6) CS(a1.w, h0, l0, 7)
      CS(a2.x, h1, l1, 0) CS(a2.y, h1, l1, 1) CS(a2.z, h1, l1, 2) CS(a2.w, h1, l1, 3)
      CS(a3.x, h1, l1, 4) CS(a3.y, h1, l1, 5) CS(a3.z, h1, l1, 6) CS(a3.w, h1, l1, 7)
      *(u16x8*)&As_hi[sr][sq]     = h0;
      *(u16x8*)&As_hi[sr][sq + 8] = h1;
      *(u16x8*)&As_lo[sr][sq]     = l0;
      *(u16x8*)&As_lo[sr][sq + 8] = l1;
    }
    // ---- stage B^T (guard n < N)
    {
      int n = bcol + sr;
      u16x8 h0 = {0,0,0,0,0,0,0,0}, h1 = h0, l0 = h0, l1 = h0;
      if (n < N) {
        const float* s = &Bt[(size_t)n * ldb + k0 + sq];
        float4 b0 = *(const float4*)(s);
        float4 b1 = *(const float4*)(s + 4);
        float4 b2 = *(const float4*)(s + 8);
        float4 b3 = *(const float4*)(s + 12);
        CS(b0.x, h0, l0, 0) CS(b0.y, h0, l0, 1) CS(b0.z, h0, l0, 2) CS(b0.w, h0, l0, 3)
        CS(b1.x, h0, l0, 4) CS(b1.y, h0, l0, 5) CS(b1.z, h0, l0, 6) CS(b1.w, h0, l0, 7)
        CS(b2.x, h1, l1, 0) CS(b2.y, h1, l1, 1) CS(b2.z, h1, l1, 2) CS(b2.w, h1, l1, 3)
        CS(b3.x, h1, l1, 4) CS(b3.y, h1, l1, 5) CS(b3.z, h1, l1, 6) CS(b3.w, h1, l1, 7)
      }
      *(u16x8*)&Bs_hi[sr][sq]     = h0;
      *(u16x8*)&Bs_hi[sr][sq + 8] = h1;
      *(u16x8*)&Bs_lo[sr][sq]     = l0;
      *(u16x8*)&Bs_lo[sr][sq + 8] = l1;
    }
    __syncthreads();

    // ---- fragments + 48 MFMA
    short8 ah[4], al[4], bh[4], bl[4];
    #pragma unroll
    for (int mf = 0; mf < 4; ++mf) {
      int r = wm * 64 + mf * 16 + fr;
      ah[mf] = *(const short8*)&As_hi[r][fk];
      al[mf] = *(const short8*)&As_lo[r][fk];
    }
    #pragma unroll
    for (int nf = 0; nf < 4; ++nf) {
      int n = wn * 64 + nf * 16 + fr;
      bh[nf] = *(const short8*)&Bs_hi[n][fk];
      bl[nf] = *(const short8*)&Bs_lo[n][fk];
    }
    #pragma unroll
    for (int mf = 0; mf < 4; ++mf)
      #pragma unroll
      for (int nf = 0; nf < 4; ++nf) {
        acc[mf][nf] = __builtin_amdgcn_mfma_f32_16x16x32_bf16(ah[mf], bh[nf], acc[mf][nf], 0, 0, 0);
        acc[mf][nf] = __builtin_amdgcn_mfma_f32_16x16x32_bf16(ah[mf], bl[nf], acc[mf][nf], 0, 0, 0);
        acc[mf][nf] = __builtin_amdgcn_mfma_f32_16x16x32_bf16(al[mf], bh[nf], acc[mf][nf], 0, 0, 0);
      }
    __syncthreads();
  }
#undef CS

  // ---- epilogue: row=(lane>>4)*4+j, col=lane&15 (m89-verified C/D layout)
  const int orow0 = brow + wm * 64 + ((lane >> 4) << 2);
  const int ocol0 = bcol + wn * 64 + fr;
  #pragma unroll
  for (int nf = 0; nf < 4; ++nf) {
    int col = ocol0 + nf * 16;
    if (col < N) {
      float bv = bias ? bias[col] : 0.f;
      #pragma unroll
      for (int mf = 0; mf < 4; ++mf) {
        #pragma unroll
        for (int j = 0; j < 4; ++j) {
          size_t idx = (size_t)(orow0 + mf * 16 + j) * ldc + col;
          float v = acc[mf][nf][j] + bv;
          if (accum) v += C[idx];
          C[idx] = v;
        }
      }
    }
  }
}

// ---------------------------------------------------------------------------
// fp32 transpose: in (R x C) -> out (C x R). 32x32 LDS tiles, 256 threads.
// ---------------------------------------------------------------------------
__global__ __launch_bounds__(256) void transpose_f32(
    const float* __restrict__ in, float* __restrict__ out, int R, int C)
{
  __shared__ float t[32][33];
  int c0 = blockIdx.x * 32, r0 = blockIdx.y * 32;
  int tx = threadIdx.x & 31, ty = threadIdx.x >> 5;   // ty 0..7
  #pragma unroll
  for (int i = 0; i < 32; i += 8) {
    int r = r0 + ty + i, c = c0 + tx;
    t[ty + i][tx] = (r < R && c < C) ? in[(size_t)r * C + c] : 0.f;
  }
  __syncthreads();
  #pragma unroll
  for (int i = 0; i < 32; i += 8) {
    int c = c0 + ty + i, r = r0 + tx;
    if (c < C && r < R) out[(size_t)c * R + r] = t[tx][ty + i];
  }
}

// ---------------------------------------------------------------------------
// Generic fp32 tiled GEMM (kept for the small Wcomb build).
// ---------------------------------------------------------------------------
#define BM 128
#define BN 128
#define BKK 16

__global__ __launch_bounds__(256) void gemm_f32(
    const float* __restrict__ A, const float* __restrict__ B,
    float* __restrict__ C, const float* __restrict__ bias,
    int N, int K, int lda, int ldb, int ldc, int accum)
{
  __shared__ float As[BKK][BM + 4];
  __shared__ float Bs[BKK][BN + 4];

  const int tid = threadIdx.x;
  const int bm = blockIdx.x * BM;
  const int bn = blockIdx.y * BN;
  const int tx = tid & 15;
  const int ty = tid >> 4;

  const int am = tid >> 2;
  const int ak = (tid & 3) * 4;
  const int bk = tid >> 5;
  const int bc = (tid & 31) * 4;

  float acc[8][8];
  #pragma unroll
  for (int i = 0; i < 8; ++i)
    #pragma unroll
    for (int j = 0; j < 8; ++j) acc[i][j] = 0.f;

  const int colb = bn + bc;
  const bool bok = (colb < N);

  for (int k0 = 0; k0 < K; k0 += BKK) {
    float4 av0 = *(const float4*)&A[(size_t)(bm + am) * lda + k0 + ak];
    float4 av1 = *(const float4*)&A[(size_t)(bm + am + 64) * lda + k0 + ak];
    As[ak + 0][am]      = av0.x; As[ak + 1][am]      = av0.y;
    As[ak + 2][am]      = av0.z; As[ak + 3][am]      = av0.w;
    As[ak + 0][am + 64] = av1.x; As[ak + 1][am + 64] = av1.y;
    As[ak + 2][am + 64] = av1.z; As[ak + 3][am + 64] = av1.w;
    float4 z4 = make_float4(0.f, 0.f, 0.f, 0.f);
    float4 bv0 = bok ? *(const float4*)&B[(size_t)(k0 + bk) * ldb + colb]     : z4;
    float4 bv1 = bok ? *(const float4*)&B[(size_t)(k0 + bk + 8) * ldb + colb] : z4;
    *(float4*)&Bs[bk][bc]     = bv0;
    *(float4*)&Bs[bk + 8][bc] = bv1;
    __syncthreads();

    #pragma unroll
    for (int k = 0; k < BKK; ++k) {
      float4 a0 = *(const float4*)&As[k][ty * 4];
      float4 a1 = *(const float4*)&As[k][64 + ty * 4];
      float4 b0 = *(const float4*)&Bs[k][tx * 4];
      float4 b1 = *(const float4*)&Bs[k][64 + tx * 4];
      float a[8] = {a0.x, a0.y, a0.z, a0.w, a1.x, a1.y, a1.z, a1.w};
      float bb[8] = {b0.x, b0.y, b0.z, b0.w, b1.x, b1.y, b1.z, b1.w};
      #pragma unroll
      for (int i = 0; i < 8; ++i)
        #pragma unroll
        for (int j = 0; j < 8; ++j)
          acc[i][j] = __builtin_fmaf(a[i], bb[j], acc[i][j]);
    }
    __syncthreads();
  }

  const int n0 = bn + tx * 4;
  const int n1 = bn + 64 + tx * 4;
  float4 bias0 = make_float4(0.f, 0.f, 0.f, 0.f), bias1 = bias0;
  if (bias) {
    if (n0 < N) bias0 = *(const float4*)&bias[n0];
    if (n1 < N) bias1 = *(const float4*)&bias[n1];
  }
  #pragma unroll
  for (int i = 0; i < 8; ++i) {
    int row = bm + ((i < 4) ? (ty * 4 + i) : (64 + ty * 4 + i - 4));
    if (n0 < N) {
      float4 v = make_float4(acc[i][0] + bias0.x, acc[i][1] + bias0.y,
                             acc[i][2] + bias0.z, acc[i][3] + bias0.w);
      if (accum) {
        float4 c = *(const float4*)&C[(size_t)row * ldc + n0];
        v.x += c.x; v.y += c.y; v.z += c.z; v.w += c.w;
      }
      *(float4*)&C[(size_t)row * ldc + n0] = v;
    }
    if (n1 < N) {
      float4 v = make_float4(acc[i][4] + bias1.x, acc[i][5] + bias1.y,
                             acc[i][6] + bias1.z, acc[i][7] + bias1.w);
      if (accum) {
        float4 c = *(const float4*)&C[(size_t)row * ldc + n1];
        v.x += c.x; v.y += c.y; v.z += c.z; v.w += c.w;
      }
      *(float4*)&C[(size_t)row * ldc + n1] = v;
    }
  }
}

// ---------------------------------------------------------------------------
// Depthwise causal (dir=0) / anti-causal (dir=1) conv + bias + silu.
// ---------------------------------------------------------------------------
__global__ __launch_bounds__(256) void conv_silu(
    const float* __restrict__ zx, const float* __restrict__ cw,
    const float* __restrict__ cb, float* __restrict__ out, int dir)
{
  int idx = blockIdx.x * 256 + threadIdx.x;
  if (idx >= MROWS * CONV_DIM) return;
  int c  = idx % CONV_DIM;
  int bl = idx / CONV_DIM;
  int l  = bl % SEQ;
  int rowbase = bl - l;

  float acc = 0.f;
  #pragma unroll
  for (int j = 0; j < D_CONV; ++j) {
    int li = dir ? (l + 4 - j) : (l - 4 + j);
    if (li >= 0 && li < SEQ)
      acc = __builtin_fmaf(cw[c * D_CONV + j],
                           zx[(size_t)(rowbase + li) * D_IN_PROJ + D_INNER + c], acc);
  }
  float v = acc + cb[c];
  out[idx] = v / (1.f + __expf(-v));
}

// ---------------------------------------------------------------------------
// Chunked selective scan (SSD decomposition) — pass1 / combine / pass3.
// ---------------------------------------------------------------------------
__global__ __launch_bounds__(64) void scan_pass1(
    const float* __restrict__ zx, const float* __restrict__ xc,
    const float* __restrict__ dtb_p, const float* __restrict__ Alog_p,
    float* __restrict__ states, float* __restrict__ Pbuf, int dir)
{
  int blk = blockIdx.x;
  int c   = blk % NCHUNK;
  int bh  = blk / NCHUNK;
  int b = bh >> 4, hd = bh & 15;
  float dtb = dtb_p[hd];
  float A   = -__expf(Alog_p[hd]);
  int p = threadIdx.x;
  const float* xrow = xc + (size_t)b * SEQ * CONV_DIM;
  const float* zrow = zx + (size_t)b * SEQ * D_IN_PROJ;

  float h[16];
  #pragma unroll
  for (int n = 0; n < 16; ++n) h[n] = 0.f;
  float P = 1.f;

  const int s0 = c * CLEN, s1 = s0 + CLEN;

  float xv0, dtr0; float4 B0[4];
  float xv1, dtr1; float4 B1[4];

#define P1LOAD(ss, XV, DTR, BB) do {                                        \
    int tt_ = dir ? (SEQ - 1 - (ss)) : (ss);                                \
    size_t xb_ = (size_t)tt_ * CONV_DIM;                                    \
    XV  = xrow[xb_ + hd * 64 + p];                                          \
    DTR = zrow[(size_t)tt_ * D_IN_PROJ + (D_INNER + CONV_DIM) + hd];        \
    const float4* B4_ = (const float4*)(xrow + xb_ + D_INNER);              \
    BB[0] = B4_[0]; BB[1] = B4_[1]; BB[2] = B4_[2]; BB[3] = B4_[3];         \
  } while (0)

  P1LOAD(s0, xv0, dtr0, B0);
  P1LOAD(s0 + 1, xv1, dtr1, B1);

  #pragma unroll 4
  for (int s = s0; s < s1; ++s) {
    float dtrb = dtr0 + dtb;
    float dt = (dtrb > 20.f) ? dtrb : log1pf(__expf(dtrb));
    float dA = __expf(dt * A);
    P *= dA;
    float dtx = dt * xv0;
#define ST1(n, Bc) h[n] = __builtin_fmaf(h[n], dA, dtx * (Bc));
    ST1(0,  B0[0].x) ST1(1,  B0[0].y) ST1(2,  B0[0].z) ST1(3,  B0[0].w)
    ST1(4,  B0[1].x) ST1(5,  B0[1].y) ST1(6,  B0[1].z) ST1(7,  B0[1].w)
    ST1(8,  B0[2].x) ST1(9,  B0[2].y) ST1(10, B0[2].z) ST1(11, B0[2].w)
    ST1(12, B0[3].x) ST1(13, B0[3].y) ST1(14, B0[3].z) ST1(15, B0[3].w)
#undef ST1
    xv0 = xv1; dtr0 = dtr1;
    #pragma unroll
    for (int q = 0; q < 4; ++q) B0[q] = B1[q];
    int sn = s + 2; if (sn > s1 - 1) sn = s1 - 1;
    P1LOAD(sn, xv1, dtr1, B1);
  }
#undef P1LOAD

  float4* sp = (float4*)&states[(((size_t)bh * NCHUNK + c) * 64 + p) * 16];
  sp[0] = make_float4(h[0],  h[1],  h[2],  h[3]);
  sp[1] = make_float4(h[4],  h[5],  h[6],  h[7]);
  sp[2] = make_float4(h[8],  h[9],  h[10], h[11]);
  sp[3] = make_float4(h[12], h[13], h[14], h[15]);
  if (p == 0) Pbuf[bh * NCHUNK + c] = P;
}

__global__ __launch_bounds__(64) void scan_combine(
    float* __restrict__ states, const float* __restrict__ Pbuf)
{
  int bh = blockIdx.x;
  int p  = threadIdx.x;
  float4 h0 = make_float4(0,0,0,0), h1 = h0, h2 = h0, h3 = h0;
  for (int c = 0; c < NCHUNK; ++c) {
    float4* sp = (float4*)&states[(((size_t)bh * NCHUNK + c) * 64 + p) * 16];
    float P = Pbuf[bh * NCHUNK + c];
    float4 s0 = sp[0], s1 = sp[1], s2 = sp[2], s3 = sp[3];
    sp[0] = h0; sp[1] = h1; sp[2] = h2; sp[3] = h3;
    h0.x = __builtin_fmaf(P, h0.x, s0.x); h0.y = __builtin_fmaf(P, h0.y, s0.y);
    h0.z = __builtin_fmaf(P, h0.z, s0.z); h0.w = __builtin_fmaf(P, h0.w, s0.w);
    h1.x = __builtin_fmaf(P, h1.x, s1.x); h1.y = __builtin_fmaf(P, h1.y, s1.y);
    h1.z = __builtin_fmaf(P, h1.z, s1.z); h1.w = __builtin_fmaf(P, h1.w, s1.w);
    h2.x = __builtin_fmaf(P, h2.x, s2.x); h2.y = __builtin_fmaf(P, h2.y, s2.y);
    h2.z = __builtin_fmaf(P, h2.z, s2.z); h2.w = __builtin_fmaf(P, h2.w, s2.w);
    h3.x = __builtin_fmaf(P, h3.x, s3.x); h3.y = __builtin_fmaf(P, h3.y, s3.y);
    h3.z = __builtin_fmaf(P, h3.z, s3.z); h3.w = __builtin_fmaf(P, h3.w, s3.w);
  }
}

__global__ __launch_bounds__(64) void scan_pass3(
    const float* __restrict__ zx, const float* __restrict__ xc,
    const float* __restrict__ dtb_p, const float* __restrict__ Alog_p,
    const float* __restrict__ D_p, const float* __restrict__ states,
    float* __restrict__ y, int dir)
{
  int blk = blockIdx.x;
  int c   = blk % NCHUNK;
  int bh  = blk / NCHUNK;
  int b = bh >> 4, hd = bh & 15;
  float dtb = dtb_p[hd];
  float A   = -__expf(Alog_p[hd]);
  float Dv  = D_p[hd];
  int p = threadIdx.x;
  const float* xrow = xc + (size_t)b * SEQ * CONV_DIM;
  const float* zrow = zx + (size_t)b * SEQ * D_IN_PROJ;
  float*       yrow = y  + (size_t)b * SEQ * D_IN_PROJ + hd * 64 + p;

  float h[16];
  {
    const float4* sp =
        (const float4*)&states[(((size_t)bh * NCHUNK + c) * 64 + p) * 16];
    float4 s0 = sp[0], s1 = sp[1], s2 = sp[2], s3 = sp[3];
    h[0]=s0.x; h[1]=s0.y; h[2]=s0.z; h[3]=s0.w;
    h[4]=s1.x; h[5]=s1.y; h[6]=s1.z; h[7]=s1.w;
    h[8]=s2.x; h[9]=s2.y; h[10]=s2.z; h[11]=s2.w;
    h[12]=s3.x; h[13]=s3.y; h[14]=s3.z; h[15]=s3.w;
  }

  const int s0i = c * CLEN, s1i = s0i + CLEN;

  float xv0, zv0, dtr0; float4 B0[4], C0[4];
  float xv1, zv1, dtr1; float4 B1[4], C1[4];

#define P3LOAD(ss, XV, ZV, DTR, BB, CC) do {                                \
    int tt_ = dir ? (SEQ - 1 - (ss)) : (ss);                                \
    size_t xb_ = (size_t)tt_ * CONV_DIM;                                    \
    size_t zb_ = (size_t)tt_ * D_IN_PROJ;                                   \
    XV  = xrow[xb_ + hd * 64 + p];                                          \
    ZV  = zrow[zb_ + hd * 64 + p];                                          \
    DTR = zrow[zb_ + (D_INNER + CONV_DIM) + hd];                            \
    const float4* B4_ = (const float4*)(xrow + xb_ + D_INNER);              \
    const float4* C4_ = (const float4*)(xrow + xb_ + D_INNER + D_STATE);    \
    BB[0] = B4_[0]; BB[1] = B4_[1]; BB[2] = B4_[2]; BB[3] = B4_[3];         \
    CC[0] = C4_[0]; CC[1] = C4_[1]; CC[2] = C4_[2]; CC[3] = C4_[3];         \
  } while (0)

  P3LOAD(s0i, xv0, zv0, dtr0, B0, C0);
  P3LOAD(s0i + 1, xv1, zv1, dtr1, B1, C1);

  #pragma unroll 4
  for (int s = s0i; s < s1i; ++s) {
    int tt = dir ? (SEQ - 1 - s) : s;
    float dtrb = dtr0 + dtb;
    float dt = (dtrb > 20.f) ? dtrb : log1pf(__expf(dtrb));
    float dA = __expf(dt * A);
    float dtx = dt * xv0;
    float yv = 0.f;
#define ST3(n, Bc, Cc) \
    h[n] = __builtin_fmaf(h[n], dA, dtx * (Bc)); \
    yv = __builtin_fmaf(h[n], (Cc), yv);
    ST3(0,  B0[0].x, C0[0].x) ST3(1,  B0[0].y, C0[0].y)
    ST3(2,  B0[0].z, C0[0].z) ST3(3,  B0[0].w, C0[0].w)
    ST3(4,  B0[1].x, C0[1].x) ST3(5,  B0[1].y, C0[1].y)
    ST3(6,  B0[1].z, C0[1].z) ST3(7,  B0[1].w, C0[1].w)
    ST3(8,  B0[2].x, C0[2].x) ST3(9,  B0[2].y, C0[2].y)
    ST3(10, B0[2].z, C0[2].z) ST3(11, B0[2].w, C0[2].w)
    ST3(12, B0[3].x, C0[3].x) ST3(13, B0[3].y, C0[3].y)
    ST3(14, B0[3].z, C0[3].z) ST3(15, B0[3].w, C0[3].w)
#undef ST3

    float sz = zv0 / (1.f + __expf(-zv0));
    yrow[(size_t)tt * D_IN_PROJ] = (yv + Dv * xv0) * sz;

    xv0 = xv1; zv0 = zv1; dtr0 = dtr1;
    #pragma unroll
    for (int q = 0; q < 4; ++q) { B0[q] = B1[q]; C0[q] = C1[q]; }
    int sn = s + 2; if (sn > s1i - 1) sn = s1i - 1;
    P3LOAD(sn, xv1, zv1, dtr1, B1, C1);
  }
#undef P3LOAD
}

// ---------------------------------------------------------------------------
// In-place gated RMSNorm over D_INNER=1024 with row stride ld.
// ---------------------------------------------------------------------------
__device__ __forceinline__ float wave_sum64(float v) {
  #pragma unroll
  for (int off = 32; off; off >>= 1) v += __shfl_xor(v, off, 64);
  return v;
}

__global__ __launch_bounds__(256) void rmsnorm_kernel(
    float* __restrict__ y, const float* __restrict__ w, int ld)
{
  int row = blockIdx.x;
  float4* yp = (float4*)(y + (size_t)row * ld);
  int c = threadIdx.x;
  float4 v = yp[c];
  float ss = v.x * v.x + v.y * v.y + v.z * v.z + v.w * v.w;
  ss = wave_sum64(ss);
  __shared__ float part[4];
  if ((threadIdx.x & 63) == 0) part[threadIdx.x >> 6] = ss;
  __syncthreads();
  float tot = part[0] + part[1] + part[2] + part[3];
  float scale = rsqrtf(tot * (1.f / D_INNER) + EPS);
  float4 wv = ((const float4*)w)[c];
  v.x *= scale * wv.x; v.y *= scale * wv.y;
  v.z *= scale * wv.z; v.w *= scale * wv.w;
  yp[c] = v;
}

// ---------------------------------------------------------------------------
// Final: h = x + x_out ; LayerNorm(512) * g + b -> out.  (xo may alias out.)
// ---------------------------------------------------------------------------
__global__ __launch_bounds__(256) void ln_final(
    const float* __restrict__ x, const float* __restrict__ xo,
    const float* __restrict__ g, const float* __restrict__ bb,
    float* __restrict__ out)
{
  int row = blockIdx.x;
  int c = threadIdx.x;
  float2 xv = ((const float2*)(x  + (size_t)row * D_MODEL))[c];
  float2 ov = ((const float2*)(xo + (size_t)row * D_MODEL))[c];
  float hx = xv.x + ov.x, hy = xv.y + ov.y;
  float s  = hx + hy;
  float sq = hx * hx + hy * hy;
  s  = wave_sum64(s);
  sq = wave_sum64(sq);
  __shared__ float ps[4], pq[4];
  if ((threadIdx.x & 63) == 0) { ps[threadIdx.x >> 6] = s; pq[threadIdx.x >> 6] = sq; }
  __syncthreads();
  float tots = ps[0] + ps[1] + ps[2] + ps[3];
  float totq = pq[0] + pq[1] + pq[2] + pq[3];
  float mu  = tots * (1.f / D_MODEL);
  float var = totq * (1.f / D_MODEL) - mu * mu;
  float inv = rsqrtf(var + EPS);
  float2 gv = ((const float2*)g)[c];
  float2 bv = ((const float2*)bb)[c];
  float2 o;
  o.x = (hx - mu) * inv * gv.x + bv.x;
  o.y = (hy - mu) * inv * gv.y + bv.y;
  ((float2*)(out + (size_t)row * D_MODEL))[c] = o;
}

// ---------------------------------------------------------------------------
extern "C" void kernel_launch(void* const* d_in, const int* in_sizes, int n_in,
                              void* d_out, int out_size, void* d_ws, size_t ws_size,
                              hipStream_t stream) {
  const float* x      = (const float*)d_in[0];
  const float* proj_W = (const float*)d_in[17];
  const float* proj_b = (const float*)d_in[18];
  const float* ln_g   = (const float*)d_in[19];
  const float* ln_b   = (const float*)d_in[20];
  float* out = (float*)d_out;

  // Workspace (sequential per-direction; same NEED as R4/R6 proven layout):
  //   zbuf    (MROWS, 2096)  in_proj out; scan y -> cols [1024,2048)
  //   convbuf (MROWS, 1056)
  //   shared region (1.574M floats), time-multiplexed within each dir:
  //     WinT (2096x512, live step 1-2) -> states+P (live 4) -> Wcomb+WcombT (6-8)
  const size_t SZ_Z  = (size_t)MROWS * D_IN_PROJ;
  const size_t SZ_C  = (size_t)MROWS * CONV_DIM;
  const size_t SZ_W  = (size_t)D_INNER * D_MODEL;        //   524,288
  const size_t SZ_ST = (size_t)256 * NCHUNK * 64 * 16;   // 1,572,864
  const size_t SZ_P  = (size_t)256 * NCHUNK;
  const size_t SZ_SH = (SZ_ST + SZ_P > SZ_W) ? (SZ_ST + SZ_P) : SZ_W;
  const size_t NEED  = (SZ_Z + SZ_C + SZ_SH) * sizeof(float);
  if (ws_size < NEED) {
    hipMemsetAsync(d_out, 0, (size_t)out_size * sizeof(float), stream);
    return;
  }
  float* zbuf    = (float*)d_ws;
  float* convbuf = zbuf + SZ_Z;
  float* shared  = convbuf + SZ_C;
  float* WinT    = shared;            // 2096x512 (1.073M <= 1.574M)
  float* states  = shared;
  float* Pbuf    = shared + SZ_ST;
  float* Wcomb   = shared;            // 1024x512
  float* WcombT  = shared + SZ_W;     // 512x1024
  float* ybuf    = zbuf + D_INNER;    // y at ld = D_IN_PROJ over dead xBC cols

  dim3 blk(256);

  for (int dir = 0; dir < 2; ++dir) {
    const float* W_in    = (const float*)d_in[dir ? 9  : 1];
    const float* conv_w  = (const float*)d_in[dir ? 10 : 2];
    const float* conv_b  = (const float*)d_in[dir ? 11 : 3];
    const float* dt_bias = (const float*)d_in[dir ? 12 : 4];
    const float* A_log   = (const float*)d_in[dir ? 13 : 5];
    const float* Dp      = (const float*)d_in[dir ? 14 : 6];
    const float* norm_w  = (const float*)d_in[dir ? 15 : 7];
    const float* W_out   = (const float*)d_in[dir ? 16 : 8];

    // 0. W_in^T (512x2096 -> 2096x512)
    transpose_f32<<<dim3(66, 16), blk, 0, stream>>>(W_in, WinT, D_MODEL, D_IN_PROJ);

    // 1. in_proj (split-bf16 MFMA): (15360,512)@(512,2096) -> zbuf
    gemm_mfma<<<dim3(MROWS / 128, 17), blk, 0, stream>>>(
        x, WinT, zbuf, nullptr,
        MROWS, D_IN_PROJ, D_MODEL, D_MODEL, D_MODEL, D_IN_PROJ, 0);

    // 2. conv + silu -> convbuf
    {
      dim3 grid((MROWS * CONV_DIM + 255) / 256);
      conv_silu<<<grid, blk, 0, stream>>>(zbuf, conv_w, conv_b, convbuf, dir);
    }
    // 3. chunked scan -> ybuf
    scan_pass1<<<dim3(256 * NCHUNK), dim3(64), 0, stream>>>(
        zbuf, convbuf, dt_bias, A_log, states, Pbuf, dir);
    scan_combine<<<dim3(256), dim3(64), 0, stream>>>(states, Pbuf);
    scan_pass3<<<dim3(256 * NCHUNK), dim3(64), 0, stream>>>(
        zbuf, convbuf, dt_bias, A_log, Dp, states, ybuf, dir);
    // 4. gated RMSNorm in place (ld = 2096)
    rmsnorm_kernel<<<dim3(MROWS), blk, 0, stream>>>(ybuf, norm_w, D_IN_PROJ);
    // 5. Wcomb = W_out @ proj_W[dir half] (1024x512@512x512), then transpose
    {
      dim3 grid(D_INNER / BM, (D_MODEL + BN - 1) / BN);
      gemm_f32<<<grid, blk, 0, stream>>>(
          W_out, proj_W + (size_t)dir * D_MODEL * D_MODEL, Wcomb, nullptr,
          D_MODEL, D_MODEL, D_MODEL, D_MODEL, D_MODEL, 0);
      transpose_f32<<<dim3(16, 32), blk, 0, stream>>>(Wcomb, WcombT, D_INNER, D_MODEL);
    }
    // 6. out accumulate (split-bf16 MFMA): d_out (+)= y @ Wcomb (+ proj_b)
    gemm_mfma<<<dim3(MROWS / 128, 4), blk, 0, stream>>>(
        ybuf, WcombT, out, dir ? nullptr : proj_b,
        MROWS, D_MODEL, D_INNER, D_IN_PROJ, D_INNER, D_MODEL, dir);
  }

  // 7. residual + LayerNorm (xo aliases out; per-thread read-then-write)
  ln_final<<<dim3(MROWS), blk, 0, stream>>>(x, out, ln_g, ln_b, out);
}

// Round 10
// 1347.738 us; speedup vs baseline: 2.1150x; 1.0015x over previous
//
#include <hip/hip_runtime.h>
#include <hip/hip_bf16.h>

#define D_MODEL   512
#define D_STATE   16
#define D_CONV    5
#define HEADDIM   64
#define D_INNER   1024
#define NHEADS    16
#define CONV_DIM  1056      // D_INNER + 2*D_STATE
#define D_IN_PROJ 2096      // 2*D_INNER + 2*D_STATE + NHEADS
#define B_SZ      16
#define SEQ       960
#define MROWS     (B_SZ*SEQ)   // 15360
#define EPS       1e-5f
#define NCHUNK    6
#define CLEN      160          // SEQ / NCHUNK

typedef __attribute__((ext_vector_type(8))) short   short8;
typedef __attribute__((ext_vector_type(8))) ushort  u16x8;
typedef __attribute__((ext_vector_type(4))) ushort  u16x4;
typedef __attribute__((ext_vector_type(4))) float   f32x4;

// ---------------------------------------------------------------------------
// split-bf16 helpers: v ~= hi + lo (each bf16, RNE), rel err ~2^-17
// ---------------------------------------------------------------------------
__device__ __forceinline__ ushort bf16_rne(float f) {
  union { float f; unsigned u; } x; x.f = f;
  unsigned u = x.u;
  return (ushort)((u + 0x7FFFu + ((u >> 16) & 1u)) >> 16);
}
__device__ __forceinline__ float bf16_f(ushort h) {
  union { unsigned u; float f; } x; x.u = ((unsigned)h) << 16;
  return x.f;
}
__device__ __forceinline__ void cvt_split(float v, ushort& h, ushort& l) {
  h = bf16_rne(v);
  l = bf16_rne(v - bf16_f(h));
}
// vector-element-safe wrapper (non-const ref can't bind to vector elements)
#define CVT_SPLIT_V(F, HV, LV, I) do { ushort th_, tl_; \
    cvt_split((F), th_, tl_); HV[I] = th_; LV[I] = tl_; } while (0)

// ---------------------------------------------------------------------------
// split_f32: fp32[4*n4] -> hi bf16, lo bf16 (flat)
// ---------------------------------------------------------------------------
__global__ __launch_bounds__(256) void split_f32(
    const float* __restrict__ in, ushort* __restrict__ hi,
    ushort* __restrict__ lo, int n4)
{
  int i = blockIdx.x * 256 + threadIdx.x;
  if (i >= n4) return;
  float4 v = ((const float4*)in)[i];
  u16x4 h, l;
  CVT_SPLIT_V(v.x, h, l, 0);
  CVT_SPLIT_V(v.y, h, l, 1);
  CVT_SPLIT_V(v.z, h, l, 2);
  CVT_SPLIT_V(v.w, h, l, 3);
  ((u16x4*)hi)[i] = h;
  ((u16x4*)lo)[i] = l;
}

// ---------------------------------------------------------------------------
// transpose_split: in (R x C fp32) -> out_hi/out_lo (C x R bf16)
// ---------------------------------------------------------------------------
__global__ __launch_bounds__(256) void transpose_split(
    const float* __restrict__ in, ushort* __restrict__ oh,
    ushort* __restrict__ ol, int R, int C)
{
  __shared__ float t[32][33];
  int c0 = blockIdx.x * 32, r0 = blockIdx.y * 32;
  int tx = threadIdx.x & 31, ty = threadIdx.x >> 5;   // ty 0..7
  #pragma unroll
  for (int i = 0; i < 32; i += 8) {
    int r = r0 + ty + i, c = c0 + tx;
    t[ty + i][tx] = (r < R && c < C) ? in[(size_t)r * C + c] : 0.f;
  }
  __syncthreads();
  #pragma unroll
  for (int i = 0; i < 32; i += 8) {
    int c = c0 + ty + i, r = r0 + tx;
    if (c < C && r < R) {
      ushort h, l;
      cvt_split(t[tx][ty + i], h, l);
      oh[(size_t)c * R + r] = h;
      ol[(size_t)c * R + r] = l;
    }
  }
}

// ---------------------------------------------------------------------------
// Pre-split bf16 MFMA GEMM: C = (accum?C:0) + A·B (+bias)
// Ah/Al: M x K bf16 (lda). Bth/Btl: N x K bf16 (ldb) = B^T. C: M x N fp32.
// M % 128 == 0, K % 32 == 0, N edge guarded. 128x128xBK32 tile, 4 waves.
// 3-term: AhBh + AhBl + AlBh.
// ---------------------------------------------------------------------------
#define LDK 40   // padded k-stride (bf16): 80B rows

__global__ __launch_bounds__(256) void gemm_mfma_bf16(
    const ushort* __restrict__ Ah, const ushort* __restrict__ Al,
    const ushort* __restrict__ Bth, const ushort* __restrict__ Btl,
    float* __restrict__ C, const float* __restrict__ bias,
    int M, int N, int K, int lda, int ldb, int ldc, int accum)
{
  __shared__ ushort As_hi[128][LDK], As_lo[128][LDK];
  __shared__ ushort Bs_hi[128][LDK], Bs_lo[128][LDK];

  const int tid  = threadIdx.x;
  const int lane = tid & 63;
  const int wave = tid >> 6;        // 4 waves, 2x2
  const int wm   = wave >> 1;
  const int wn   = wave & 1;
  const int brow = blockIdx.x * 128;
  const int bcol = blockIdx.y * 128;

  const int sr = tid >> 1;          // staged row 0..127
  const int sq = (tid & 1) * 16;    // k offset 0/16

  f32x4 acc[4][4];
  #pragma unroll
  for (int i = 0; i < 4; ++i)
    #pragma unroll
    for (int j = 0; j < 4; ++j) acc[i][j] = f32x4{0.f, 0.f, 0.f, 0.f};

  const int fr = lane & 15;
  const int fk = (lane >> 4) * 8;

  for (int k0 = 0; k0 < K; k0 += 32) {
    // ---- stage A (M % 128 == 0: always valid)
    {
      size_t off = (size_t)(brow + sr) * lda + k0 + sq;
      *(u16x8*)&As_hi[sr][sq]     = *(const u16x8*)&Ah[off];
      *(u16x8*)&As_hi[sr][sq + 8] = *(const u16x8*)&Ah[off + 8];
      *(u16x8*)&As_lo[sr][sq]     = *(const u16x8*)&Al[off];
      *(u16x8*)&As_lo[sr][sq + 8] = *(const u16x8*)&Al[off + 8];
    }
    // ---- stage B^T (guard n < N)
    {
      int n = bcol + sr;
      u16x8 z8 = {0,0,0,0,0,0,0,0};
      u16x8 h0 = z8, h1 = z8, l0 = z8, l1 = z8;
      if (n < N) {
        size_t off = (size_t)n * ldb + k0 + sq;
        h0 = *(const u16x8*)&Bth[off];
        h1 = *(const u16x8*)&Bth[off + 8];
        l0 = *(const u16x8*)&Btl[off];
        l1 = *(const u16x8*)&Btl[off + 8];
      }
      *(u16x8*)&Bs_hi[sr][sq]     = h0;
      *(u16x8*)&Bs_hi[sr][sq + 8] = h1;
      *(u16x8*)&Bs_lo[sr][sq]     = l0;
      *(u16x8*)&Bs_lo[sr][sq + 8] = l1;
    }
    __syncthreads();

    // ---- fragments + 48 MFMA
    short8 ah[4], al[4], bh[4], bl[4];
    #pragma unroll
    for (int mf = 0; mf < 4; ++mf) {
      int r = wm * 64 + mf * 16 + fr;
      ah[mf] = *(const short8*)&As_hi[r][fk];
      al[mf] = *(const short8*)&As_lo[r][fk];
    }
    #pragma unroll
    for (int nf = 0; nf < 4; ++nf) {
      int n = wn * 64 + nf * 16 + fr;
      bh[nf] = *(const short8*)&Bs_hi[n][fk];
      bl[nf] = *(const short8*)&Bs_lo[n][fk];
    }
    #pragma unroll
    for (int mf = 0; mf < 4; ++mf)
      #pragma unroll
      for (int nf = 0; nf < 4; ++nf) {
        acc[mf][nf] = __builtin_amdgcn_mfma_f32_16x16x32_bf16(ah[mf], bh[nf], acc[mf][nf], 0, 0, 0);
        acc[mf][nf] = __builtin_amdgcn_mfma_f32_16x16x32_bf16(ah[mf], bl[nf], acc[mf][nf], 0, 0, 0);
        acc[mf][nf] = __builtin_amdgcn_mfma_f32_16x16x32_bf16(al[mf], bh[nf], acc[mf][nf], 0, 0, 0);
      }
    __syncthreads();
  }

  // ---- epilogue: row=(lane>>4)*4+j, col=lane&15 (m89-verified C/D layout)
  const int orow0 = brow + wm * 64 + ((lane >> 4) << 2);
  const int ocol0 = bcol + wn * 64 + fr;
  #pragma unroll
  for (int nf = 0; nf < 4; ++nf) {
    int col = ocol0 + nf * 16;
    if (col < N) {
      float bv = bias ? bias[col] : 0.f;
      #pragma unroll
      for (int mf = 0; mf < 4; ++mf) {
        #pragma unroll
        for (int j = 0; j < 4; ++j) {
          size_t idx = (size_t)(orow0 + mf * 16 + j) * ldc + col;
          float v = acc[mf][nf][j] + bv;
          if (accum) v += C[idx];
          C[idx] = v;
        }
      }
    }
  }
}

// ---------------------------------------------------------------------------
// Generic fp32 tiled GEMM (kept for the small Wcomb build).
// ---------------------------------------------------------------------------
#define BM 128
#define BN 128
#define BKK 16

__global__ __launch_bounds__(256) void gemm_f32(
    const float* __restrict__ A, const float* __restrict__ B,
    float* __restrict__ C, const float* __restrict__ bias,
    int N, int K, int lda, int ldb, int ldc, int accum)
{
  __shared__ float As[BKK][BM + 4];
  __shared__ float Bs[BKK][BN + 4];

  const int tid = threadIdx.x;
  const int bm = blockIdx.x * BM;
  const int bn = blockIdx.y * BN;
  const int tx = tid & 15;
  const int ty = tid >> 4;

  const int am = tid >> 2;
  const int ak = (tid & 3) * 4;
  const int bk = tid >> 5;
  const int bc = (tid & 31) * 4;

  float acc[8][8];
  #pragma unroll
  for (int i = 0; i < 8; ++i)
    #pragma unroll
    for (int j = 0; j < 8; ++j) acc[i][j] = 0.f;

  const int colb = bn + bc;
  const bool bok = (colb < N);

  for (int k0 = 0; k0 < K; k0 += BKK) {
    float4 av0 = *(const float4*)&A[(size_t)(bm + am) * lda + k0 + ak];
    float4 av1 = *(const float4*)&A[(size_t)(bm + am + 64) * lda + k0 + ak];
    As[ak + 0][am]      = av0.x; As[ak + 1][am]      = av0.y;
    As[ak + 2][am]      = av0.z; As[ak + 3][am]      = av0.w;
    As[ak + 0][am + 64] = av1.x; As[ak + 1][am + 64] = av1.y;
    As[ak + 2][am + 64] = av1.z; As[ak + 3][am + 64] = av1.w;
    float4 z4 = make_float4(0.f, 0.f, 0.f, 0.f);
    float4 bv0 = bok ? *(const float4*)&B[(size_t)(k0 + bk) * ldb + colb]     : z4;
    float4 bv1 = bok ? *(const float4*)&B[(size_t)(k0 + bk + 8) * ldb + colb] : z4;
    *(float4*)&Bs[bk][bc]     = bv0;
    *(float4*)&Bs[bk + 8][bc] = bv1;
    __syncthreads();

    #pragma unroll
    for (int k = 0; k < BKK; ++k) {
      float4 a0 = *(const float4*)&As[k][ty * 4];
      float4 a1 = *(const float4*)&As[k][64 + ty * 4];
      float4 b0 = *(const float4*)&Bs[k][tx * 4];
      float4 b1 = *(const float4*)&Bs[k][64 + tx * 4];
      float a[8] = {a0.x, a0.y, a0.z, a0.w, a1.x, a1.y, a1.z, a1.w};
      float bb[8] = {b0.x, b0.y, b0.z, b0.w, b1.x, b1.y, b1.z, b1.w};
      #pragma unroll
      for (int i = 0; i < 8; ++i)
        #pragma unroll
        for (int j = 0; j < 8; ++j)
          acc[i][j] = __builtin_fmaf(a[i], bb[j], acc[i][j]);
    }
    __syncthreads();
  }

  const int n0 = bn + tx * 4;
  const int n1 = bn + 64 + tx * 4;
  float4 bias0 = make_float4(0.f, 0.f, 0.f, 0.f), bias1 = bias0;
  if (bias) {
    if (n0 < N) bias0 = *(const float4*)&bias[n0];
    if (n1 < N) bias1 = *(const float4*)&bias[n1];
  }
  #pragma unroll
  for (int i = 0; i < 8; ++i) {
    int row = bm + ((i < 4) ? (ty * 4 + i) : (64 + ty * 4 + i - 4));
    if (n0 < N) {
      float4 v = make_float4(acc[i][0] + bias0.x, acc[i][1] + bias0.y,
                             acc[i][2] + bias0.z, acc[i][3] + bias0.w);
      if (accum) {
        float4 c = *(const float4*)&C[(size_t)row * ldc + n0];
        v.x += c.x; v.y += c.y; v.z += c.z; v.w += c.w;
      }
      *(float4*)&C[(size_t)row * ldc + n0] = v;
    }
    if (n1 < N) {
      float4 v = make_float4(acc[i][4] + bias1.x, acc[i][5] + bias1.y,
                             acc[i][6] + bias1.z, acc[i][7] + bias1.w);
      if (accum) {
        float4 c = *(const float4*)&C[(size_t)row * ldc + n1];
        v.x += c.x; v.y += c.y; v.z += c.z; v.w += c.w;
      }
      *(float4*)&C[(size_t)row * ldc + n1] = v;
    }
  }
}

// ---------------------------------------------------------------------------
// Depthwise causal (dir=0) / anti-causal (dir=1) conv + bias + silu.
// ---------------------------------------------------------------------------
__global__ __launch_bounds__(256) void conv_silu(
    const float* __restrict__ zx, const float* __restrict__ cw,
    const float* __restrict__ cb, float* __restrict__ out, int dir)
{
  int idx = blockIdx.x * 256 + threadIdx.x;
  if (idx >= MROWS * CONV_DIM) return;
  int c  = idx % CONV_DIM;
  int bl = idx / CONV_DIM;
  int l  = bl % SEQ;
  int rowbase = bl - l;

  float acc = 0.f;
  #pragma unroll
  for (int j = 0; j < D_CONV; ++j) {
    int li = dir ? (l + 4 - j) : (l - 4 + j);
    if (li >= 0 && li < SEQ)
      acc = __builtin_fmaf(cw[c * D_CONV + j],
                           zx[(size_t)(rowbase + li) * D_IN_PROJ + D_INNER + c], acc);
  }
  float v = acc + cb[c];
  out[idx] = v / (1.f + __expf(-v));
}

// ---------------------------------------------------------------------------
// Chunked selective scan (SSD decomposition) — pass1 / combine / pass3.
// ---------------------------------------------------------------------------
__global__ __launch_bounds__(64) void scan_pass1(
    const float* __restrict__ zx, const float* __restrict__ xc,
    const float* __restrict__ dtb_p, const float* __restrict__ Alog_p,
    float* __restrict__ states, float* __restrict__ Pbuf, int dir)
{
  int blk = blockIdx.x;
  int c   = blk % NCHUNK;
  int bh  = blk / NCHUNK;
  int b = bh >> 4, hd = bh & 15;
  float dtb = dtb_p[hd];
  float A   = -__expf(Alog_p[hd]);
  int p = threadIdx.x;
  const float* xrow = xc + (size_t)b * SEQ * CONV_DIM;
  const float* zrow = zx + (size_t)b * SEQ * D_IN_PROJ;

  float h[16];
  #pragma unroll
  for (int n = 0; n < 16; ++n) h[n] = 0.f;
  float P = 1.f;

  const int s0 = c * CLEN, s1 = s0 + CLEN;

  float xv0, dtr0; float4 B0[4];
  float xv1, dtr1; float4 B1[4];

#define P1LOAD(ss, XV, DTR, BB) do {                                        \
    int tt_ = dir ? (SEQ - 1 - (ss)) : (ss);                                \
    size_t xb_ = (size_t)tt_ * CONV_DIM;                                    \
    XV  = xrow[xb_ + hd * 64 + p];                                          \
    DTR = zrow[(size_t)tt_ * D_IN_PROJ + (D_INNER + CONV_DIM) + hd];        \
    const float4* B4_ = (const float4*)(xrow + xb_ + D_INNER);              \
    BB[0] = B4_[0]; BB[1] = B4_[1]; BB[2] = B4_[2]; BB[3] = B4_[3];         \
  } while (0)

  P1LOAD(s0, xv0, dtr0, B0);
  P1LOAD(s0 + 1, xv1, dtr1, B1);

  #pragma unroll 4
  for (int s = s0; s < s1; ++s) {
    float dtrb = dtr0 + dtb;
    float dt = (dtrb > 20.f) ? dtrb : log1pf(__expf(dtrb));
    float dA = __expf(dt * A);
    P *= dA;
    float dtx = dt * xv0;
#define ST1(n, Bc) h[n] = __builtin_fmaf(h[n], dA, dtx * (Bc));
    ST1(0,  B0[0].x) ST1(1,  B0[0].y) ST1(2,  B0[0].z) ST1(3,  B0[0].w)
    ST1(4,  B0[1].x) ST1(5,  B0[1].y) ST1(6,  B0[1].z) ST1(7,  B0[1].w)
    ST1(8,  B0[2].x) ST1(9,  B0[2].y) ST1(10, B0[2].z) ST1(11, B0[2].w)
    ST1(12, B0[3].x) ST1(13, B0[3].y) ST1(14, B0[3].z) ST1(15, B0[3].w)
#undef ST1
    xv0 = xv1; dtr0 = dtr1;
    #pragma unroll
    for (int q = 0; q < 4; ++q) B0[q] = B1[q];
    int sn = s + 2; if (sn > s1 - 1) sn = s1 - 1;
    P1LOAD(sn, xv1, dtr1, B1);
  }
#undef P1LOAD

  float4* sp = (float4*)&states[(((size_t)bh * NCHUNK + c) * 64 + p) * 16];
  sp[0] = make_float4(h[0],  h[1],  h[2],  h[3]);
  sp[1] = make_float4(h[4],  h[5],  h[6],  h[7]);
  sp[2] = make_float4(h[8],  h[9],  h[10], h[11]);
  sp[3] = make_float4(h[12], h[13], h[14], h[15]);
  if (p == 0) Pbuf[bh * NCHUNK + c] = P;
}

__global__ __launch_bounds__(64) void scan_combine(
    float* __restrict__ states, const float* __restrict__ Pbuf)
{
  int bh = blockIdx.x;
  int p  = threadIdx.x;
  float4 h0 = make_float4(0,0,0,0), h1 = h0, h2 = h0, h3 = h0;
  for (int c = 0; c < NCHUNK; ++c) {
    float4* sp = (float4*)&states[(((size_t)bh * NCHUNK + c) * 64 + p) * 16];
    float P = Pbuf[bh * NCHUNK + c];
    float4 s0 = sp[0], s1 = sp[1], s2 = sp[2], s3 = sp[3];
    sp[0] = h0; sp[1] = h1; sp[2] = h2; sp[3] = h3;
    h0.x = __builtin_fmaf(P, h0.x, s0.x); h0.y = __builtin_fmaf(P, h0.y, s0.y);
    h0.z = __builtin_fmaf(P, h0.z, s0.z); h0.w = __builtin_fmaf(P, h0.w, s0.w);
    h1.x = __builtin_fmaf(P, h1.x, s1.x); h1.y = __builtin_fmaf(P, h1.y, s1.y);
    h1.z = __builtin_fmaf(P, h1.z, s1.z); h1.w = __builtin_fmaf(P, h1.w, s1.w);
    h2.x = __builtin_fmaf(P, h2.x, s2.x); h2.y = __builtin_fmaf(P, h2.y, s2.y);
    h2.z = __builtin_fmaf(P, h2.z, s2.z); h2.w = __builtin_fmaf(P, h2.w, s2.w);
    h3.x = __builtin_fmaf(P, h3.x, s3.x); h3.y = __builtin_fmaf(P, h3.y, s3.y);
    h3.z = __builtin_fmaf(P, h3.z, s3.z); h3.w = __builtin_fmaf(P, h3.w, s3.w);
  }
}

__global__ __launch_bounds__(64) void scan_pass3(
    const float* __restrict__ zx, const float* __restrict__ xc,
    const float* __restrict__ dtb_p, const float* __restrict__ Alog_p,
    const float* __restrict__ D_p, const float* __restrict__ states,
    float* __restrict__ y, int dir)
{
  int blk = blockIdx.x;
  int c   = blk % NCHUNK;
  int bh  = blk / NCHUNK;
  int b = bh >> 4, hd = bh & 15;
  float dtb = dtb_p[hd];
  float A   = -__expf(Alog_p[hd]);
  float Dv  = D_p[hd];
  int p = threadIdx.x;
  const float* xrow = xc + (size_t)b * SEQ * CONV_DIM;
  const float* zrow = zx + (size_t)b * SEQ * D_IN_PROJ;
  float*       yrow = y  + (size_t)b * SEQ * D_IN_PROJ + hd * 64 + p;

  float h[16];
  {
    const float4* sp =
        (const float4*)&states[(((size_t)bh * NCHUNK + c) * 64 + p) * 16];
    float4 s0 = sp[0], s1 = sp[1], s2 = sp[2], s3 = sp[3];
    h[0]=s0.x; h[1]=s0.y; h[2]=s0.z; h[3]=s0.w;
    h[4]=s1.x; h[5]=s1.y; h[6]=s1.z; h[7]=s1.w;
    h[8]=s2.x; h[9]=s2.y; h[10]=s2.z; h[11]=s2.w;
    h[12]=s3.x; h[13]=s3.y; h[14]=s3.z; h[15]=s3.w;
  }

  const int s0i = c * CLEN, s1i = s0i + CLEN;

  float xv0, zv0, dtr0; float4 B0[4], C0[4];
  float xv1, zv1, dtr1; float4 B1[4], C1[4];

#define P3LOAD(ss, XV, ZV, DTR, BB, CC) do {                                \
    int tt_ = dir ? (SEQ - 1 - (ss)) : (ss);                                \
    size_t xb_ = (size_t)tt_ * CONV_DIM;                                    \
    size_t zb_ = (size_t)tt_ * D_IN_PROJ;                                   \
    XV  = xrow[xb_ + hd * 64 + p];                                          \
    ZV  = zrow[zb_ + hd * 64 + p];                                          \
    DTR = zrow[zb_ + (D_INNER + CONV_DIM) + hd];                            \
    const float4* B4_ = (const float4*)(xrow + xb_ + D_INNER);              \
    const float4* C4_ = (const float4*)(xrow + xb_ + D_INNER + D_STATE);    \
    BB[0] = B4_[0]; BB[1] = B4_[1]; BB[2] = B4_[2]; BB[3] = B4_[3];         \
    CC[0] = C4_[0]; CC[1] = C4_[1]; CC[2] = C4_[2]; CC[3] = C4_[3];         \
  } while (0)

  P3LOAD(s0i, xv0, zv0, dtr0, B0, C0);
  P3LOAD(s0i + 1, xv1, zv1, dtr1, B1, C1);

  #pragma unroll 4
  for (int s = s0i; s < s1i; ++s) {
    int tt = dir ? (SEQ - 1 - s) : s;
    float dtrb = dtr0 + dtb;
    float dt = (dtrb > 20.f) ? dtrb : log1pf(__expf(dtrb));
    float dA = __expf(dt * A);
    float dtx = dt * xv0;
    float yv = 0.f;
#define ST3(n, Bc, Cc) \
    h[n] = __builtin_fmaf(h[n], dA, dtx * (Bc)); \
    yv = __builtin_fmaf(h[n], (Cc), yv);
    ST3(0,  B0[0].x, C0[0].x) ST3(1,  B0[0].y, C0[0].y)
    ST3(2,  B0[0].z, C0[0].z) ST3(3,  B0[0].w, C0[0].w)
    ST3(4,  B0[1].x, C0[1].x) ST3(5,  B0[1].y, C0[1].y)
    ST3(6,  B0[1].z, C0[1].z) ST3(7,  B0[1].w, C0[1].w)
    ST3(8,  B0[2].x, C0[2].x) ST3(9,  B0[2].y, C0[2].y)
    ST3(10, B0[2].z, C0[2].z) ST3(11, B0[2].w, C0[2].w)
    ST3(12, B0[3].x, C0[3].x) ST3(13, B0[3].y, C0[3].y)
    ST3(14, B0[3].z, C0[3].z) ST3(15, B0[3].w, C0[3].w)
#undef ST3

    float sz = zv0 / (1.f + __expf(-zv0));
    yrow[(size_t)tt * D_IN_PROJ] = (yv + Dv * xv0) * sz;

    xv0 = xv1; zv0 = zv1; dtr0 = dtr1;
    #pragma unroll
    for (int q = 0; q < 4; ++q) { B0[q] = B1[q]; C0[q] = C1[q]; }
    int sn = s + 2; if (sn > s1i - 1) sn = s1i - 1;
    P3LOAD(sn, xv1, zv1, dtr1, B1, C1);
  }
#undef P3LOAD
}

// ---------------------------------------------------------------------------
// Gated RMSNorm + bf16 split: read y (ld 2096), write y_hi/y_lo (ld 1024).
// ---------------------------------------------------------------------------
__device__ __forceinline__ float wave_sum64(float v) {
  #pragma unroll
  for (int off = 32; off; off >>= 1) v += __shfl_xor(v, off, 64);
  return v;
}

__global__ __launch_bounds__(256) void rmsnorm_split(
    const float* __restrict__ y, const float* __restrict__ w,
    ushort* __restrict__ yh, ushort* __restrict__ yl)
{
  int row = blockIdx.x;
  const float4* yp = (const float4*)(y + (size_t)row * D_IN_PROJ);
  int c = threadIdx.x;                      // 256 * 4 = 1024
  float4 v = yp[c];
  float ss = v.x * v.x + v.y * v.y + v.z * v.z + v.w * v.w;
  ss = wave_sum64(ss);
  __shared__ float part[4];
  if ((threadIdx.x & 63) == 0) part[threadIdx.x >> 6] = ss;
  __syncthreads();
  float tot = part[0] + part[1] + part[2] + part[3];
  float scale = rsqrtf(tot * (1.f / D_INNER) + EPS);
  float4 wv = ((const float4*)w)[c];
  u16x4 h, l;
  CVT_SPLIT_V(v.x * scale * wv.x, h, l, 0);
  CVT_SPLIT_V(v.y * scale * wv.y, h, l, 1);
  CVT_SPLIT_V(v.z * scale * wv.z, h, l, 2);
  CVT_SPLIT_V(v.w * scale * wv.w, h, l, 3);
  ((u16x4*)(yh + (size_t)row * D_INNER))[c] = h;
  ((u16x4*)(yl + (size_t)row * D_INNER))[c] = l;
}

// ---------------------------------------------------------------------------
// Final: h = x + x_out ; LayerNorm(512) * g + b -> out.  (xo may alias out.)
// ---------------------------------------------------------------------------
__global__ __launch_bounds__(256) void ln_final(
    const float* __restrict__ x, const float* __restrict__ xo,
    const float* __restrict__ g, const float* __restrict__ bb,
    float* __restrict__ out)
{
  int row = blockIdx.x;
  int c = threadIdx.x;
  float2 xv = ((const float2*)(x  + (size_t)row * D_MODEL))[c];
  float2 ov = ((const float2*)(xo + (size_t)row * D_MODEL))[c];
  float hx = xv.x + ov.x, hy = xv.y + ov.y;
  float s  = hx + hy;
  float sq = hx * hx + hy * hy;
  s  = wave_sum64(s);
  sq = wave_sum64(sq);
  __shared__ float ps[4], pq[4];
  if ((threadIdx.x & 63) == 0) { ps[threadIdx.x >> 6] = s; pq[threadIdx.x >> 6] = sq; }
  __syncthreads();
  float tots = ps[0] + ps[1] + ps[2] + ps[3];
  float totq = pq[0] + pq[1] + pq[2] + pq[3];
  float mu  = tots * (1.f / D_MODEL);
  float var = totq * (1.f / D_MODEL) - mu * mu;
  float inv = rsqrtf(var + EPS);
  float2 gv = ((const float2*)g)[c];
  float2 bv = ((const float2*)bb)[c];
  float2 o;
  o.x = (hx - mu) * inv * gv.x + bv.x;
  o.y = (hy - mu) * inv * gv.y + bv.y;
  ((float2*)(out + (size_t)row * D_MODEL))[c] = o;
}

// ---------------------------------------------------------------------------
extern "C" void kernel_launch(void* const* d_in, const int* in_sizes, int n_in,
                              void* d_out, int out_size, void* d_ws, size_t ws_size,
                              hipStream_t stream) {
  const float* x      = (const float*)d_in[0];
  const float* proj_W = (const float*)d_in[17];
  const float* proj_b = (const float*)d_in[18];
  const float* ln_g   = (const float*)d_in[19];
  const float* ln_b   = (const float*)d_in[20];
  float* out = (float*)d_out;

  // Workspace (sequential per-direction; NEED unchanged from proven R6/R7):
  //   zbuf    (MROWS, 2096)  in_proj out; scan y -> cols [1024,2048)
  //   convbuf (MROWS, 1056)  time-multiplexed:
  //     pre-conv:  x_hi/x_lo (bf16) + WinT_hi/lo (bf16)   [8.94M float-eq]
  //     conv..scan: conv+silu output (fp32)
  //     post-scan: y_hi/y_lo (bf16)                       [15.73M float-eq]
  //   shared: states+P (scan) / Wcomb fp32 + WcombT_hi/lo bf16 (post-scan)
  const size_t SZ_Z  = (size_t)MROWS * D_IN_PROJ;
  const size_t SZ_C  = (size_t)MROWS * CONV_DIM;
  const size_t SZ_W  = (size_t)D_INNER * D_MODEL;        //   524,288
  const size_t SZ_ST = (size_t)256 * NCHUNK * 64 * 16;   // 1,572,864
  const size_t SZ_P  = (size_t)256 * NCHUNK;
  const size_t SZ_SH = (SZ_ST + SZ_P > SZ_W) ? (SZ_ST + SZ_P) : SZ_W;
  const size_t NEED  = (SZ_Z + SZ_C + SZ_SH) * sizeof(float);
  if (ws_size < NEED) {
    (void)hipMemsetAsync(d_out, 0, (size_t)out_size * sizeof(float), stream);
    return;
  }
  float* zbuf    = (float*)d_ws;
  float* convbuf = zbuf + SZ_Z;
  float* shared  = convbuf + SZ_C;
  float* states  = shared;
  float* Pbuf    = shared + SZ_ST;
  float* ybuf    = zbuf + D_INNER;    // y fp32 at ld = D_IN_PROJ (dead xBC cols)

  // bf16 staging overlays in convbuf region (pre-conv)
  ushort* x_hi    = (ushort*)convbuf;
  ushort* x_lo    = x_hi + (size_t)MROWS * D_MODEL;
  ushort* WinT_hi = x_lo + (size_t)MROWS * D_MODEL;
  ushort* WinT_lo = WinT_hi + (size_t)D_IN_PROJ * D_MODEL;
  // post-scan overlays
  ushort* y_hi    = (ushort*)convbuf;
  ushort* y_lo    = y_hi + (size_t)MROWS * D_INNER;
  float*  Wcomb   = shared;
  ushort* WcT_hi  = (ushort*)(shared + SZ_W);
  ushort* WcT_lo  = WcT_hi + (size_t)D_MODEL * D_INNER;

  dim3 blk(256);

  for (int dir = 0; dir < 2; ++dir) {
    const float* W_in    = (const float*)d_in[dir ? 9  : 1];
    const float* conv_w  = (const float*)d_in[dir ? 10 : 2];
    const float* conv_b  = (const float*)d_in[dir ? 11 : 3];
    const float* dt_bias = (const float*)d_in[dir ? 12 : 4];
    const float* A_log   = (const float*)d_in[dir ? 13 : 5];
    const float* Dp      = (const float*)d_in[dir ? 14 : 6];
    const float* norm_w  = (const float*)d_in[dir ? 15 : 7];
    const float* W_out   = (const float*)d_in[dir ? 16 : 8];

    // 0a. split x -> bf16 hi/lo (per dir: convbuf gets clobbered by conv)
    {
      int n4 = MROWS * D_MODEL / 4;
      split_f32<<<dim3((n4 + 255) / 256), blk, 0, stream>>>(x, x_hi, x_lo, n4);
    }
    // 0b. W_in (512x2096) -> WinT hi/lo (2096x512 bf16)
    transpose_split<<<dim3(66, 16), blk, 0, stream>>>(
        W_in, WinT_hi, WinT_lo, D_MODEL, D_IN_PROJ);

    // 1. in_proj (pre-split bf16 MFMA): (15360,512)@(512,2096) -> zbuf
    gemm_mfma_bf16<<<dim3(MROWS / 128, 17), blk, 0, stream>>>(
        x_hi, x_lo, WinT_hi, WinT_lo, zbuf, nullptr,
        MROWS, D_IN_PROJ, D_MODEL, D_MODEL, D_MODEL, D_IN_PROJ, 0);

    // 2. conv + silu -> convbuf (x_hi/WinT overlays now dead)
    {
      dim3 grid((MROWS * CONV_DIM + 255) / 256);
      conv_silu<<<grid, blk, 0, stream>>>(zbuf, conv_w, conv_b, convbuf, dir);
    }
    // 3. chunked scan -> ybuf (fp32, in zbuf dead cols)
    scan_pass1<<<dim3(256 * NCHUNK), dim3(64), 0, stream>>>(
        zbuf, convbuf, dt_bias, A_log, states, Pbuf, dir);
    scan_combine<<<dim3(256), dim3(64), 0, stream>>>(states, Pbuf);
    scan_pass3<<<dim3(256 * NCHUNK), dim3(64), 0, stream>>>(
        zbuf, convbuf, dt_bias, A_log, Dp, states, ybuf, dir);
    // 4. gated RMSNorm + split -> y_hi/y_lo (convbuf region; conv data dead)
    rmsnorm_split<<<dim3(MROWS), blk, 0, stream>>>(ybuf, norm_w, y_hi, y_lo);
    // 5. Wcomb = W_out @ proj_W[dir half]; then transpose+split
    {
      dim3 grid(D_INNER / BM, (D_MODEL + BN - 1) / BN);
      gemm_f32<<<grid, blk, 0, stream>>>(
          W_out, proj_W + (size_t)dir * D_MODEL * D_MODEL, Wcomb, nullptr,
          D_MODEL, D_MODEL, D_MODEL, D_MODEL, D_MODEL, 0);
      transpose_split<<<dim3(16, 32), blk, 0, stream>>>(
          Wcomb, WcT_hi, WcT_lo, D_INNER, D_MODEL);
    }
    // 6. out accumulate (pre-split bf16 MFMA): d_out (+)= y @ Wcomb (+ bias)
    gemm_mfma_bf16<<<dim3(MROWS / 128, 4), blk, 0, stream>>>(
        y_hi, y_lo, WcT_hi, WcT_lo, out, dir ? nullptr : proj_b,
        MROWS, D_MODEL, D_INNER, D_INNER, D_INNER, D_MODEL, dir);
  }

  // 7. residual + LayerNorm (xo aliases out; per-thread read-then-write)
  ln_final<<<dim3(MROWS), blk, 0, stream>>>(x, out, ln_g, ln_b, out);
}

// Round 11
// 1293.971 us; speedup vs baseline: 2.2028x; 1.0416x over previous
//
#include <hip/hip_runtime.h>
#include <hip/hip_bf16.h>

#define D_MODEL   512
#define D_STATE   16
#define D_CONV    5
#define HEADDIM   64
#define D_INNER   1024
#define NHEADS    16
#define CONV_DIM  1056      // D_INNER + 2*D_STATE
#define D_IN_PROJ 2096      // 2*D_INNER + 2*D_STATE + NHEADS
#define B_SZ      16
#define SEQ       960
#define MROWS     (B_SZ*SEQ)   // 15360
#define EPS       1e-5f

typedef __attribute__((ext_vector_type(8))) short   short8;
typedef __attribute__((ext_vector_type(8))) ushort  u16x8;
typedef __attribute__((ext_vector_type(4))) ushort  u16x4;
typedef __attribute__((ext_vector_type(4))) float   f32x4;

// ---------------------------------------------------------------------------
// split-bf16 helpers: v ~= hi + lo (each bf16, RNE), rel err ~2^-17
// ---------------------------------------------------------------------------
__device__ __forceinline__ ushort bf16_rne(float f) {
  union { float f; unsigned u; } x; x.f = f;
  unsigned u = x.u;
  return (ushort)((u + 0x7FFFu + ((u >> 16) & 1u)) >> 16);
}
__device__ __forceinline__ float bf16_f(ushort h) {
  union { unsigned u; float f; } x; x.u = ((unsigned)h) << 16;
  return x.f;
}
__device__ __forceinline__ void cvt_split(float v, ushort& h, ushort& l) {
  h = bf16_rne(v);
  l = bf16_rne(v - bf16_f(h));
}
#define CVT_SPLIT_V(F, HV, LV, I) do { ushort th_, tl_; \
    cvt_split((F), th_, tl_); HV[I] = th_; LV[I] = tl_; } while (0)

// async global->LDS, 16B per lane; LDS dest = wave-uniform base + lane*16
__device__ __forceinline__ void gload16(const ushort* g, ushort* l) {
  __builtin_amdgcn_global_load_lds(
      (const __attribute__((address_space(1))) void*)g,
      (__attribute__((address_space(3))) void*)l, 16, 0, 0);
}

// ---------------------------------------------------------------------------
// split_f32: fp32[4*n4] -> hi bf16, lo bf16 (flat)
// ---------------------------------------------------------------------------
__global__ __launch_bounds__(256) void split_f32(
    const float* __restrict__ in, ushort* __restrict__ hi,
    ushort* __restrict__ lo, int n4)
{
  int i = blockIdx.x * 256 + threadIdx.x;
  if (i >= n4) return;
  float4 v = ((const float4*)in)[i];
  u16x4 h, l;
  CVT_SPLIT_V(v.x, h, l, 0);
  CVT_SPLIT_V(v.y, h, l, 1);
  CVT_SPLIT_V(v.z, h, l, 2);
  CVT_SPLIT_V(v.w, h, l, 3);
  ((u16x4*)hi)[i] = h;
  ((u16x4*)lo)[i] = l;
}

// ---------------------------------------------------------------------------
// transpose_split: in (R x C fp32) -> out_hi/out_lo (C x R bf16)
// ---------------------------------------------------------------------------
__global__ __launch_bounds__(256) void transpose_split(
    const float* __restrict__ in, ushort* __restrict__ oh,
    ushort* __restrict__ ol, int R, int C)
{
  __shared__ float t[32][33];
  int c0 = blockIdx.x * 32, r0 = blockIdx.y * 32;
  int tx = threadIdx.x & 31, ty = threadIdx.x >> 5;   // ty 0..7
  #pragma unroll
  for (int i = 0; i < 32; i += 8) {
    int r = r0 + ty + i, c = c0 + tx;
    t[ty + i][tx] = (r < R && c < C) ? in[(size_t)r * C + c] : 0.f;
  }
  __syncthreads();
  #pragma unroll
  for (int i = 0; i < 32; i += 8) {
    int c = c0 + ty + i, r = r0 + tx;
    if (c < C && r < R) {
      ushort h, l;
      cvt_split(t[tx][ty + i], h, l);
      oh[(size_t)c * R + r] = h;
      ol[(size_t)c * R + r] = l;
    }
  }
}

// ---------------------------------------------------------------------------
// Pre-split bf16 MFMA GEMM, fragment-major LDS + global_load_lds staging.
// Ah (+loA = Al): M x K bf16 (lda). Bth (+loB = Btl): N x K bf16 (ldb) = B^T.
// C: M x N fp32 (ldc). M%128==0, K%32==0, N edge clamped on load / guarded
// on store. Tile 128x128x32, 4 waves (2x2). 3-term: AhBh + AhBl + AlBh.
//
// LDS chunk layout per matrix (8KB = 512 chunks x 16B):
//   chunk(mf,kg,fr) = mf*64 + kg*16 + fr  holds A[row=mf*16+fr][k=kg*8..+8).
// Staging wave w, issue i: chunks [w*128+i*64, +64) -> uniform LDS base +
// lane*16 (hw); per-lane global addr = row (w*2+i)*16+(lane&15),
// k-off ((lane>>4)&3)*8.  Fragment read: lane reads chunk mfg*64+lane ->
// linear 16B/lane => zero bank conflicts both sides.
// ---------------------------------------------------------------------------
__global__ __launch_bounds__(256) void gemm_mfma_bf16(
    const ushort* __restrict__ Ah, size_t loA,
    const ushort* __restrict__ Bth, size_t loB,
    float* __restrict__ C, const float* __restrict__ bias,
    int M, int N, int K, int lda, int ldb, int ldc, int accum)
{
  __shared__ ushort lds[16384];   // [0)Ah [4096)Al [8192)Bh [12288)Bl

  const int tid  = threadIdx.x;
  const int lane = tid & 63;
  const int wave = tid >> 6;        // 4 waves, 2x2
  const int wm   = wave >> 1;
  const int wn   = wave & 1;
  const int brow = blockIdx.x * 128;
  const int bcol = blockIdx.y * 128;

  const int fr  = lane & 15;
  const int kg8 = ((lane >> 4) & 3) * 8;

  // staging source pointers (per-lane), advanced by 32 per K-step
  const int srow0 = (wave * 2 + 0) * 16 + fr;
  const int srow1 = (wave * 2 + 1) * 16 + fr;
  int bn0 = bcol + srow0; if (bn0 > N - 1) bn0 = N - 1;
  int bn1 = bcol + srow1; if (bn1 > N - 1) bn1 = N - 1;
  const ushort* pA0 = Ah  + (size_t)(brow + srow0) * lda + kg8;
  const ushort* pA1 = Ah  + (size_t)(brow + srow1) * lda + kg8;
  const ushort* pB0 = Bth + (size_t)bn0 * ldb + kg8;
  const ushort* pB1 = Bth + (size_t)bn1 * ldb + kg8;

  // wave-uniform LDS dest bases (ushort offsets)
  const int ld0 = wave * 1024;
  const int ld1 = wave * 1024 + 512;

  f32x4 acc[4][4];
  #pragma unroll
  for (int i = 0; i < 4; ++i)
    #pragma unroll
    for (int j = 0; j < 4; ++j) acc[i][j] = f32x4{0.f, 0.f, 0.f, 0.f};

  for (int k0 = 0; k0 < K; k0 += 32) {
    // ---- async stage: 8 x global_load_lds dwordx4
    gload16(pA0,        &lds[ld0]);
    gload16(pA1,        &lds[ld1]);
    gload16(pA0 + loA,  &lds[4096 + ld0]);
    gload16(pA1 + loA,  &lds[4096 + ld1]);
    gload16(pB0,        &lds[8192 + ld0]);
    gload16(pB1,        &lds[8192 + ld1]);
    gload16(pB0 + loB,  &lds[12288 + ld0]);
    gload16(pB1 + loB,  &lds[12288 + ld1]);
    __syncthreads();   // compiler drains vmcnt before barrier -> tile ready

    // ---- fragments (conflict-free linear reads) + 48 MFMA
    short8 ah[4], al[4], bh[4], bl[4];
    #pragma unroll
    for (int f = 0; f < 4; ++f) {
      int amfg = wm * 4 + f;
      int bnfg = wn * 4 + f;
      ah[f] = *(const short8*)&lds[amfg * 512 + lane * 8];
      al[f] = *(const short8*)&lds[4096 + amfg * 512 + lane * 8];
      bh[f] = *(const short8*)&lds[8192 + bnfg * 512 + lane * 8];
      bl[f] = *(const short8*)&lds[12288 + bnfg * 512 + lane * 8];
    }
    #pragma unroll
    for (int mf = 0; mf < 4; ++mf)
      #pragma unroll
      for (int nf = 0; nf < 4; ++nf) {
        acc[mf][nf] = __builtin_amdgcn_mfma_f32_16x16x32_bf16(ah[mf], bh[nf], acc[mf][nf], 0, 0, 0);
        acc[mf][nf] = __builtin_amdgcn_mfma_f32_16x16x32_bf16(ah[mf], bl[nf], acc[mf][nf], 0, 0, 0);
        acc[mf][nf] = __builtin_amdgcn_mfma_f32_16x16x32_bf16(al[mf], bh[nf], acc[mf][nf], 0, 0, 0);
      }
    __syncthreads();

    pA0 += 32; pA1 += 32; pB0 += 32; pB1 += 32;
  }

  // ---- epilogue: row=(lane>>4)*4+j, col=lane&15 (m89-verified C/D layout)
  const int orow0 = brow + wm * 64 + ((lane >> 4) << 2);
  const int ocol0 = bcol + wn * 64 + fr;
  #pragma unroll
  for (int nf = 0; nf < 4; ++nf) {
    int col = ocol0 + nf * 16;
    if (col < N) {
      float bv = bias ? bias[col] : 0.f;
      #pragma unroll
      for (int mf = 0; mf < 4; ++mf) {
        #pragma unroll
        for (int j = 0; j < 4; ++j) {
          size_t idx = (size_t)(orow0 + mf * 16 + j) * ldc + col;
          float v = acc[mf][nf][j] + bv;
          if (accum) v += C[idx];
          C[idx] = v;
        }
      }
    }
  }
}

// ---------------------------------------------------------------------------
// Generic fp32 tiled GEMM (kept for the small Wcomb build).
// ---------------------------------------------------------------------------
#define BM 128
#define BN 128
#define BKK 16

__global__ __launch_bounds__(256) void gemm_f32(
    const float* __restrict__ A, const float* __restrict__ B,
    float* __restrict__ C, const float* __restrict__ bias,
    int N, int K, int lda, int ldb, int ldc, int accum)
{
  __shared__ float As[BKK][BM + 4];
  __shared__ float Bs[BKK][BN + 4];

  const int tid = threadIdx.x;
  const int bm = blockIdx.x * BM;
  const int bn = blockIdx.y * BN;
  const int tx = tid & 15;
  const int ty = tid >> 4;

  const int am = tid >> 2;
  const int ak = (tid & 3) * 4;
  const int bk = tid >> 5;
  const int bc = (tid & 31) * 4;

  float acc[8][8];
  #pragma unroll
  for (int i = 0; i < 8; ++i)
    #pragma unroll
    for (int j = 0; j < 8; ++j) acc[i][j] = 0.f;

  const int colb = bn + bc;
  const bool bok = (colb < N);

  for (int k0 = 0; k0 < K; k0 += BKK) {
    float4 av0 = *(const float4*)&A[(size_t)(bm + am) * lda + k0 + ak];
    float4 av1 = *(const float4*)&A[(size_t)(bm + am + 64) * lda + k0 + ak];
    As[ak + 0][am]      = av0.x; As[ak + 1][am]      = av0.y;
    As[ak + 2][am]      = av0.z; As[ak + 3][am]      = av0.w;
    As[ak + 0][am + 64] = av1.x; As[ak + 1][am + 64] = av1.y;
    As[ak + 2][am + 64] = av1.z; As[ak + 3][am + 64] = av1.w;
    float4 z4 = make_float4(0.f, 0.f, 0.f, 0.f);
    float4 bv0 = bok ? *(const float4*)&B[(size_t)(k0 + bk) * ldb + colb]     : z4;
    float4 bv1 = bok ? *(const float4*)&B[(size_t)(k0 + bk + 8) * ldb + colb] : z4;
    *(float4*)&Bs[bk][bc]     = bv0;
    *(float4*)&Bs[bk + 8][bc] = bv1;
    __syncthreads();

    #pragma unroll
    for (int k = 0; k < BKK; ++k) {
      float4 a0 = *(const float4*)&As[k][ty * 4];
      float4 a1 = *(const float4*)&As[k][64 + ty * 4];
      float4 b0 = *(const float4*)&Bs[k][tx * 4];
      float4 b1 = *(const float4*)&Bs[k][64 + tx * 4];
      float a[8] = {a0.x, a0.y, a0.z, a0.w, a1.x, a1.y, a1.z, a1.w};
      float bb[8] = {b0.x, b0.y, b0.z, b0.w, b1.x, b1.y, b1.z, b1.w};
      #pragma unroll
      for (int i = 0; i < 8; ++i)
        #pragma unroll
        for (int j = 0; j < 8; ++j)
          acc[i][j] = __builtin_fmaf(a[i], bb[j], acc[i][j]);
    }
    __syncthreads();
  }

  const int n0 = bn + tx * 4;
  const int n1 = bn + 64 + tx * 4;
  float4 bias0 = make_float4(0.f, 0.f, 0.f, 0.f), bias1 = bias0;
  if (bias) {
    if (n0 < N) bias0 = *(const float4*)&bias[n0];
    if (n1 < N) bias1 = *(const float4*)&bias[n1];
  }
  #pragma unroll
  for (int i = 0; i < 8; ++i) {
    int row = bm + ((i < 4) ? (ty * 4 + i) : (64 + ty * 4 + i - 4));
    if (n0 < N) {
      float4 v = make_float4(acc[i][0] + bias0.x, acc[i][1] + bias0.y,
                             acc[i][2] + bias0.z, acc[i][3] + bias0.w);
      if (accum) {
        float4 c = *(const float4*)&C[(size_t)row * ldc + n0];
        v.x += c.x; v.y += c.y; v.z += c.z; v.w += c.w;
      }
      *(float4*)&C[(size_t)row * ldc + n0] = v;
    }
    if (n1 < N) {
      float4 v = make_float4(acc[i][4] + bias1.x, acc[i][5] + bias1.y,
                             acc[i][6] + bias1.z, acc[i][7] + bias1.w);
      if (accum) {
        float4 c = *(const float4*)&C[(size_t)row * ldc + n1];
        v.x += c.x; v.y += c.y; v.z += c.z; v.w += c.w;
      }
      *(float4*)&C[(size_t)row * ldc + n1] = v;
    }
  }
}

// ---------------------------------------------------------------------------
// Depthwise causal (dir=0) / anti-causal (dir=1) conv + bias + silu.
// ---------------------------------------------------------------------------
__global__ __launch_bounds__(256) void conv_silu(
    const float* __restrict__ zx, const float* __restrict__ cw,
    const float* __restrict__ cb, float* __restrict__ out, int dir)
{
  int idx = blockIdx.x * 256 + threadIdx.x;
  if (idx >= MROWS * CONV_DIM) return;
  int c  = idx % CONV_DIM;
  int bl = idx / CONV_DIM;
  int l  = bl % SEQ;
  int rowbase = bl - l;

  float acc = 0.f;
  #pragma unroll
  for (int j = 0; j < D_CONV; ++j) {
    int li = dir ? (l + 4 - j) : (l - 4 + j);
    if (li >= 0 && li < SEQ)
      acc = __builtin_fmaf(cw[c * D_CONV + j],
                           zx[(size_t)(rowbase + li) * D_IN_PROJ + D_INNER + c], acc);
  }
  float v = acc + cb[c];
  out[idx] = v / (1.f + __expf(-v));
}

// ---------------------------------------------------------------------------
// Chunked selective scan (SSD decomposition) — pass1 / combine / pass3.
// Runtime nchunk/clen (chosen from ws_size; deterministic per session).
// ---------------------------------------------------------------------------
__global__ __launch_bounds__(64) void scan_pass1(
    const float* __restrict__ zx, const float* __restrict__ xc,
    const float* __restrict__ dtb_p, const float* __restrict__ Alog_p,
    float* __restrict__ states, float* __restrict__ Pbuf, int dir,
    int nchunk, int clen)
{
  int blk = blockIdx.x;
  int c   = blk % nchunk;
  int bh  = blk / nchunk;
  int b = bh >> 4, hd = bh & 15;
  float dtb = dtb_p[hd];
  float A   = -__expf(Alog_p[hd]);
  int p = threadIdx.x;
  const float* xrow = xc + (size_t)b * SEQ * CONV_DIM;
  const float* zrow = zx + (size_t)b * SEQ * D_IN_PROJ;

  float h[16];
  #pragma unroll
  for (int n = 0; n < 16; ++n) h[n] = 0.f;
  float P = 1.f;

  const int s0 = c * clen, s1 = s0 + clen;

  float xv0, dtr0; float4 B0[4];
  float xv1, dtr1; float4 B1[4];

#define P1LOAD(ss, XV, DTR, BB) do {                                        \
    int tt_ = dir ? (SEQ - 1 - (ss)) : (ss);                                \
    size_t xb_ = (size_t)tt_ * CONV_DIM;                                    \
    XV  = xrow[xb_ + hd * 64 + p];                                          \
    DTR = zrow[(size_t)tt_ * D_IN_PROJ + (D_INNER + CONV_DIM) + hd];        \
    const float4* B4_ = (const float4*)(xrow + xb_ + D_INNER);              \
    BB[0] = B4_[0]; BB[1] = B4_[1]; BB[2] = B4_[2]; BB[3] = B4_[3];         \
  } while (0)

  P1LOAD(s0, xv0, dtr0, B0);
  P1LOAD(s0 + 1, xv1, dtr1, B1);

  #pragma unroll 4
  for (int s = s0; s < s1; ++s) {
    float dtrb = dtr0 + dtb;
    float dt = (dtrb > 20.f) ? dtrb : log1pf(__expf(dtrb));
    float dA = __expf(dt * A);
    P *= dA;
    float dtx = dt * xv0;
#define ST1(n, Bc) h[n] = __builtin_fmaf(h[n], dA, dtx * (Bc));
    ST1(0,  B0[0].x) ST1(1,  B0[0].y) ST1(2,  B0[0].z) ST1(3,  B0[0].w)
    ST1(4,  B0[1].x) ST1(5,  B0[1].y) ST1(6,  B0[1].z) ST1(7,  B0[1].w)
    ST1(8,  B0[2].x) ST1(9,  B0[2].y) ST1(10, B0[2].z) ST1(11, B0[2].w)
    ST1(12, B0[3].x) ST1(13, B0[3].y) ST1(14, B0[3].z) ST1(15, B0[3].w)
#undef ST1
    xv0 = xv1; dtr0 = dtr1;
    #pragma unroll
    for (int q = 0; q < 4; ++q) B0[q] = B1[q];
    int sn = s + 2; if (sn > s1 - 1) sn = s1 - 1;
    P1LOAD(sn, xv1, dtr1, B1);
  }
#undef P1LOAD

  float4* sp = (float4*)&states[(((size_t)bh * nchunk + c) * 64 + p) * 16];
  sp[0] = make_float4(h[0],  h[1],  h[2],  h[3]);
  sp[1] = make_float4(h[4],  h[5],  h[6],  h[7]);
  sp[2] = make_float4(h[8],  h[9],  h[10], h[11]);
  sp[3] = make_float4(h[12], h[13], h[14], h[15]);
  if (p == 0) Pbuf[bh * nchunk + c] = P;
}

__global__ __launch_bounds__(64) void scan_combine(
    float* __restrict__ states, const float* __restrict__ Pbuf, int nchunk)
{
  int bh = blockIdx.x;
  int p  = threadIdx.x;
  float4 h0 = make_float4(0,0,0,0), h1 = h0, h2 = h0, h3 = h0;
  for (int c = 0; c < nchunk; ++c) {
    float4* sp = (float4*)&states[(((size_t)bh * nchunk + c) * 64 + p) * 16];
    float P = Pbuf[bh * nchunk + c];
    float4 s0 = sp[0], s1 = sp[1], s2 = sp[2], s3 = sp[3];
    sp[0] = h0; sp[1] = h1; sp[2] = h2; sp[3] = h3;
    h0.x = __builtin_fmaf(P, h0.x, s0.x); h0.y = __builtin_fmaf(P, h0.y, s0.y);
    h0.z = __builtin_fmaf(P, h0.z, s0.z); h0.w = __builtin_fmaf(P, h0.w, s0.w);
    h1.x = __builtin_fmaf(P, h1.x, s1.x); h1.y = __builtin_fmaf(P, h1.y, s1.y);
    h1.z = __builtin_fmaf(P, h1.z, s1.z); h1.w = __builtin_fmaf(P, h1.w, s1.w);
    h2.x = __builtin_fmaf(P, h2.x, s2.x); h2.y = __builtin_fmaf(P, h2.y, s2.y);
    h2.z = __builtin_fmaf(P, h2.z, s2.z); h2.w = __builtin_fmaf(P, h2.w, s2.w);
    h3.x = __builtin_fmaf(P, h3.x, s3.x); h3.y = __builtin_fmaf(P, h3.y, s3.y);
    h3.z = __builtin_fmaf(P, h3.z, s3.z); h3.w = __builtin_fmaf(P, h3.w, s3.w);
  }
}

__global__ __launch_bounds__(64) void scan_pass3(
    const float* __restrict__ zx, const float* __restrict__ xc,
    const float* __restrict__ dtb_p, const float* __restrict__ Alog_p,
    const float* __restrict__ D_p, const float* __restrict__ states,
    float* __restrict__ y, int dir, int nchunk, int clen)
{
  int blk = blockIdx.x;
  int c   = blk % nchunk;
  int bh  = blk / nchunk;
  int b = bh >> 4, hd = bh & 15;
  float dtb = dtb_p[hd];
  float A   = -__expf(Alog_p[hd]);
  float Dv  = D_p[hd];
  int p = threadIdx.x;
  const float* xrow = xc + (size_t)b * SEQ * CONV_DIM;
  const float* zrow = zx + (size_t)b * SEQ * D_IN_PROJ;
  float*       yrow = y  + (size_t)b * SEQ * D_IN_PROJ + hd * 64 + p;

  float h[16];
  {
    const float4* sp =
        (const float4*)&states[(((size_t)bh * nchunk + c) * 64 + p) * 16];
    float4 s0 = sp[0], s1 = sp[1], s2 = sp[2], s3 = sp[3];
    h[0]=s0.x; h[1]=s0.y; h[2]=s0.z; h[3]=s0.w;
    h[4]=s1.x; h[5]=s1.y; h[6]=s1.z; h[7]=s1.w;
    h[8]=s2.x; h[9]=s2.y; h[10]=s2.z; h[11]=s2.w;
    h[12]=s3.x; h[13]=s3.y; h[14]=s3.z; h[15]=s3.w;
  }

  const int s0i = c * clen, s1i = s0i + clen;

  float xv0, zv0, dtr0; float4 B0[4], C0[4];
  float xv1, zv1, dtr1; float4 B1[4], C1[4];

#define P3LOAD(ss, XV, ZV, DTR, BB, CC) do {                                \
    int tt_ = dir ? (SEQ - 1 - (ss)) : (ss);                                \
    size_t xb_ = (size_t)tt_ * CONV_DIM;                                    \
    size_t zb_ = (size_t)tt_ * D_IN_PROJ;                                   \
    XV  = xrow[xb_ + hd * 64 + p];                                          \
    ZV  = zrow[zb_ + hd * 64 + p];                                          \
    DTR = zrow[zb_ + (D_INNER + CONV_DIM) + hd];                            \
    const float4* B4_ = (const float4*)(xrow + xb_ + D_INNER);              \
    const float4* C4_ = (const float4*)(xrow + xb_ + D_INNER + D_STATE);    \
    BB[0] = B4_[0]; BB[1] = B4_[1]; BB[2] = B4_[2]; BB[3] = B4_[3];         \
    CC[0] = C4_[0]; CC[1] = C4_[1]; CC[2] = C4_[2]; CC[3] = C4_[3];         \
  } while (0)

  P3LOAD(s0i, xv0, zv0, dtr0, B0, C0);
  P3LOAD(s0i + 1, xv1, zv1, dtr1, B1, C1);

  #pragma unroll 4
  for (int s = s0i; s < s1i; ++s) {
    int tt = dir ? (SEQ - 1 - s) : s;
    float dtrb = dtr0 + dtb;
    float dt = (dtrb > 20.f) ? dtrb : log1pf(__expf(dtrb));
    float dA = __expf(dt * A);
    float dtx = dt * xv0;
    float yv = 0.f;
#define ST3(n, Bc, Cc) \
    h[n] = __builtin_fmaf(h[n], dA, dtx * (Bc)); \
    yv = __builtin_fmaf(h[n], (Cc), yv);
    ST3(0,  B0[0].x, C0[0].x) ST3(1,  B0[0].y, C0[0].y)
    ST3(2,  B0[0].z, C0[0].z) ST3(3,  B0[0].w, C0[0].w)
    ST3(4,  B0[1].x, C0[1].x) ST3(5,  B0[1].y, C0[1].y)
    ST3(6,  B0[1].z, C0[1].z) ST3(7,  B0[1].w, C0[1].w)
    ST3(8,  B0[2].x, C0[2].x) ST3(9,  B0[2].y, C0[2].y)
    ST3(10, B0[2].z, C0[2].z) ST3(11, B0[2].w, C0[2].w)
    ST3(12, B0[3].x, C0[3].x) ST3(13, B0[3].y, C0[3].y)
    ST3(14, B0[3].z, C0[3].z) ST3(15, B0[3].w, C0[3].w)
#undef ST3

    float sz = zv0 / (1.f + __expf(-zv0));
    yrow[(size_t)tt * D_IN_PROJ] = (yv + Dv * xv0) * sz;

    xv0 = xv1; zv0 = zv1; dtr0 = dtr1;
    #pragma unroll
    for (int q = 0; q < 4; ++q) { B0[q] = B1[q]; C0[q] = C1[q]; }
    int sn = s + 2; if (sn > s1i - 1) sn = s1i - 1;
    P3LOAD(sn, xv1, zv1, dtr1, B1, C1);
  }
#undef P3LOAD
}

// ---------------------------------------------------------------------------
// Gated RMSNorm + bf16 split: read y (ld 2096), write y_hi/y_lo (ld 1024).
// ---------------------------------------------------------------------------
__device__ __forceinline__ float wave_sum64(float v) {
  #pragma unroll
  for (int off = 32; off; off >>= 1) v += __shfl_xor(v, off, 64);
  return v;
}

__global__ __launch_bounds__(256) void rmsnorm_split(
    const float* __restrict__ y, const float* __restrict__ w,
    ushort* __restrict__ yh, ushort* __restrict__ yl)
{
  int row = blockIdx.x;
  const float4* yp = (const float4*)(y + (size_t)row * D_IN_PROJ);
  int c = threadIdx.x;                      // 256 * 4 = 1024
  float4 v = yp[c];
  float ss = v.x * v.x + v.y * v.y + v.z * v.z + v.w * v.w;
  ss = wave_sum64(ss);
  __shared__ float part[4];
  if ((threadIdx.x & 63) == 0) part[threadIdx.x >> 6] = ss;
  __syncthreads();
  float tot = part[0] + part[1] + part[2] + part[3];
  float scale = rsqrtf(tot * (1.f / D_INNER) + EPS);
  float4 wv = ((const float4*)w)[c];
  u16x4 h, l;
  CVT_SPLIT_V(v.x * scale * wv.x, h, l, 0);
  CVT_SPLIT_V(v.y * scale * wv.y, h, l, 1);
  CVT_SPLIT_V(v.z * scale * wv.z, h, l, 2);
  CVT_SPLIT_V(v.w * scale * wv.w, h, l, 3);
  ((u16x4*)(yh + (size_t)row * D_INNER))[c] = h;
  ((u16x4*)(yl + (size_t)row * D_INNER))[c] = l;
}

// ---------------------------------------------------------------------------
// Final: h = x + x_out ; LayerNorm(512) * g + b -> out.  (xo may alias out.)
// ---------------------------------------------------------------------------
__global__ __launch_bounds__(256) void ln_final(
    const float* __restrict__ x, const float* __restrict__ xo,
    const float* __restrict__ g, const float* __restrict__ bb,
    float* __restrict__ out)
{
  int row = blockIdx.x;
  int c = threadIdx.x;
  float2 xv = ((const float2*)(x  + (size_t)row * D_MODEL))[c];
  float2 ov = ((const float2*)(xo + (size_t)row * D_MODEL))[c];
  float hx = xv.x + ov.x, hy = xv.y + ov.y;
  float s  = hx + hy;
  float sq = hx * hx + hy * hy;
  s  = wave_sum64(s);
  sq = wave_sum64(sq);
  __shared__ float ps[4], pq[4];
  if ((threadIdx.x & 63) == 0) { ps[threadIdx.x >> 6] = s; pq[threadIdx.x >> 6] = sq; }
  __syncthreads();
  float tots = ps[0] + ps[1] + ps[2] + ps[3];
  float totq = pq[0] + pq[1] + pq[2] + pq[3];
  float mu  = tots * (1.f / D_MODEL);
  float var = totq * (1.f / D_MODEL) - mu * mu;
  float inv = rsqrtf(var + EPS);
  float2 gv = ((const float2*)g)[c];
  float2 bv = ((const float2*)bb)[c];
  float2 o;
  o.x = (hx - mu) * inv * gv.x + bv.x;
  o.y = (hy - mu) * inv * gv.y + bv.y;
  ((float2*)(out + (size_t)row * D_MODEL))[c] = o;
}

// ---------------------------------------------------------------------------
extern "C" void kernel_launch(void* const* d_in, const int* in_sizes, int n_in,
                              void* d_out, int out_size, void* d_ws, size_t ws_size,
                              hipStream_t stream) {
  const float* x      = (const float*)d_in[0];
  const float* proj_W = (const float*)d_in[17];
  const float* proj_b = (const float*)d_in[18];
  const float* ln_g   = (const float*)d_in[19];
  const float* ln_b   = (const float*)d_in[20];
  float* out = (float*)d_out;

  // Workspace layout as proven in R6-R10 (zbuf + convbuf + shared region).
  // Scan chunk depth adapts to ws_size (deterministic: ws_size fixed/session).
  const size_t SZ_Z    = (size_t)MROWS * D_IN_PROJ;
  const size_t SZ_C    = (size_t)MROWS * CONV_DIM;
  const size_t SZ_W    = (size_t)D_INNER * D_MODEL;            //   524,288
  const size_t SZ_POST = SZ_W + (size_t)D_MODEL * D_INNER;     // Wcomb + WcT hi/lo
  int nchunk = 0;
  {
    const int cand[3] = {20, 12, 6};   // CLEN 48 / 80 / 160
    for (int i = 0; i < 3 && !nchunk; ++i) {
      size_t st = (size_t)256 * cand[i] * 64 * 16 + (size_t)256 * cand[i];
      size_t sh = st > SZ_POST ? st : SZ_POST;
      if (ws_size >= (SZ_Z + SZ_C + sh) * sizeof(float)) nchunk = cand[i];
    }
  }
  if (!nchunk) {
    (void)hipMemsetAsync(d_out, 0, (size_t)out_size * sizeof(float), stream);
    return;
  }
  const int clen = SEQ / nchunk;
  const size_t SZ_ST = (size_t)256 * nchunk * 64 * 16;

  float* zbuf    = (float*)d_ws;
  float* convbuf = zbuf + SZ_Z;
  float* shared  = convbuf + SZ_C;
  float* states  = shared;
  float* Pbuf    = shared + SZ_ST;
  float* ybuf    = zbuf + D_INNER;    // y fp32 at ld = D_IN_PROJ (dead xBC cols)

  // bf16 staging overlays in convbuf region (pre-conv); hi and lo contiguous
  // so the MFMA kernel takes hi pointer + lo offset.
  ushort* x_hi    = (ushort*)convbuf;
  const size_t loX = (size_t)MROWS * D_MODEL;
  ushort* x_lo    = x_hi + loX;
  ushort* WinT_hi = x_lo + loX;
  const size_t loWin = (size_t)D_IN_PROJ * D_MODEL;
  ushort* WinT_lo = WinT_hi + loWin;
  // post-scan overlays
  ushort* y_hi    = (ushort*)convbuf;
  const size_t loY = (size_t)MROWS * D_INNER;
  ushort* y_lo    = y_hi + loY;
  float*  Wcomb   = shared;
  ushort* WcT_hi  = (ushort*)(shared + SZ_W);
  const size_t loWc = (size_t)D_MODEL * D_INNER;
  ushort* WcT_lo  = WcT_hi + loWc;

  dim3 blk(256);

  for (int dir = 0; dir < 2; ++dir) {
    const float* W_in    = (const float*)d_in[dir ? 9  : 1];
    const float* conv_w  = (const float*)d_in[dir ? 10 : 2];
    const float* conv_b  = (const float*)d_in[dir ? 11 : 3];
    const float* dt_bias = (const float*)d_in[dir ? 12 : 4];
    const float* A_log   = (const float*)d_in[dir ? 13 : 5];
    const float* Dp      = (const float*)d_in[dir ? 14 : 6];
    const float* norm_w  = (const float*)d_in[dir ? 15 : 7];
    const float* W_out   = (const float*)d_in[dir ? 16 : 8];

    // 0a. split x -> bf16 hi/lo (per dir: convbuf gets clobbered by conv)
    {
      int n4 = MROWS * D_MODEL / 4;
      split_f32<<<dim3((n4 + 255) / 256), blk, 0, stream>>>(x, x_hi, x_lo, n4);
    }
    // 0b. W_in (512x2096) -> WinT hi/lo (2096x512 bf16)
    transpose_split<<<dim3(66, 16), blk, 0, stream>>>(
        W_in, WinT_hi, WinT_lo, D_MODEL, D_IN_PROJ);

    // 1. in_proj (bf16 MFMA, gload_lds staging): (15360,512)@(512,2096)
    gemm_mfma_bf16<<<dim3(MROWS / 128, 17), blk, 0, stream>>>(
        x_hi, loX, WinT_hi, loWin, zbuf, nullptr,
        MROWS, D_IN_PROJ, D_MODEL, D_MODEL, D_MODEL, D_IN_PROJ, 0);

    // 2. conv + silu -> convbuf (x_hi/WinT overlays now dead)
    {
      dim3 grid((MROWS * CONV_DIM + 255) / 256);
      conv_silu<<<grid, blk, 0, stream>>>(zbuf, conv_w, conv_b, convbuf, dir);
    }
    // 3. chunked scan -> ybuf (fp32, in zbuf dead cols)
    scan_pass1<<<dim3(256 * nchunk), dim3(64), 0, stream>>>(
        zbuf, convbuf, dt_bias, A_log, states, Pbuf, dir, nchunk, clen);
    scan_combine<<<dim3(256), dim3(64), 0, stream>>>(states, Pbuf, nchunk);
    scan_pass3<<<dim3(256 * nchunk), dim3(64), 0, stream>>>(
        zbuf, convbuf, dt_bias, A_log, Dp, states, ybuf, dir, nchunk, clen);
    // 4. gated RMSNorm + split -> y_hi/y_lo (convbuf region; conv data dead)
    rmsnorm_split<<<dim3(MROWS), blk, 0, stream>>>(ybuf, norm_w, y_hi, y_lo);
    // 5. Wcomb = W_out @ proj_W[dir half]; then transpose+split
    {
      dim3 grid(D_INNER / BM, (D_MODEL + BN - 1) / BN);
      gemm_f32<<<grid, blk, 0, stream>>>(
          W_out, proj_W + (size_t)dir * D_MODEL * D_MODEL, Wcomb, nullptr,
          D_MODEL, D_MODEL, D_MODEL, D_MODEL, D_MODEL, 0);
      transpose_split<<<dim3(16, 32), blk, 0, stream>>>(
          Wcomb, WcT_hi, WcT_lo, D_INNER, D_MODEL);
    }
    // 6. out accumulate (bf16 MFMA): d_out (+)= y @ Wcomb (+ bias)
    gemm_mfma_bf16<<<dim3(MROWS / 128, 4), blk, 0, stream>>>(
        y_hi, loY, WcT_hi, loWc, out, dir ? nullptr : proj_b,
        MROWS, D_MODEL, D_INNER, D_INNER, D_INNER, D_MODEL, dir);
  }

  // 7. residual + LayerNorm (xo aliases out; per-thread read-then-write)
  ln_final<<<dim3(MROWS), blk, 0, stream>>>(x, out, ln_g, ln_b, out);
}